// Round 6
// baseline (33974.216 us; speedup 1.0000x reference)
//
#include <hip/hip_runtime.h>
#include <hip/hip_bf16.h>

typedef __bf16 bf16_t;
typedef bf16_t bfx8 __attribute__((ext_vector_type(8)));
typedef float  fx4  __attribute__((ext_vector_type(4)));

#define TT     256
#define BB     512
#define INDIM  512
#define NGENRE 5
#define HD     2048
#define LATD   1024
#define LATM   1019
#define XK     517
#define XKP    576

// ---------------- helpers ----------------
__device__ __forceinline__ bf16_t f2b(float f) {
  unsigned u = __builtin_bit_cast(unsigned, f);
  u += 0x7fffu + ((u >> 16) & 1u);
  unsigned short s = (unsigned short)(u >> 16);
  return __builtin_bit_cast(bf16_t, s);
}
__device__ __forceinline__ float sigmoidf_(float x) { return 1.0f / (1.0f + __expf(-x)); }

__device__ __forceinline__ void gload16(const bf16_t* g, bf16_t* l) {
  __builtin_amdgcn_global_load_lds((const __attribute__((address_space(1))) void*)g,
                                   (__attribute__((address_space(3))) void*)l,
                                   16, 0, 0);
}
__device__ __forceinline__ void wait_vm0()  { asm volatile("s_waitcnt vmcnt(0)" ::: "memory"); }
__device__ __forceinline__ void wait_vm3()  { asm volatile("s_waitcnt vmcnt(3)" ::: "memory"); }
__device__ __forceinline__ void wait_vm4()  { asm volatile("s_waitcnt vmcnt(4)" ::: "memory"); }
__device__ __forceinline__ void wait_vm6()  { asm volatile("s_waitcnt vmcnt(6)" ::: "memory"); }
__device__ __forceinline__ void wait_vm8()  { asm volatile("s_waitcnt vmcnt(8)" ::: "memory"); }
__device__ __forceinline__ void wait_lgkm0() { asm volatile("s_waitcnt lgkmcnt(0)" ::: "memory"); }

// ---------------- fp32 -> bf16 cast with row/col zero-padding ----------------
__global__ void wcast_pad(const float* __restrict__ src, bf16_t* __restrict__ dst,
                          int rows_src, int rows_pad, int K, int ldp) {
  for (int r = blockIdx.x; r < rows_pad; r += gridDim.x)
    for (int c = threadIdx.x; c < ldp; c += 256)
      dst[(size_t)r * ldp + c] = (r < rows_src && c < K) ? f2b(src[(size_t)r * K + c]) : f2b(0.0f);
}

// ---------------- fused GRU step v5 ----------------
// Tile: 128 rows x 32 j-cols (x3 gates). 512 thr = 8 waves (4m x 2j), each wave
// 32 rows x 16 j x 3 gates: 12 MFMA : 10 ds_read per K64. Grid 256 (1 block/CU,
// 2 waves/SIMD). Depth-3 staging, role-split producers: waves 0-3 stage A
// (4 gload16/stage), waves 4-7 stage B (3/stage); per-wave counted vmcnt.
// Chunked XCD swizzle, m-fastest ordering (B L2-reuse across m-blocks).
// acc slots: 0=r 1=z 2=inn(phase0) 3=hn(phase1)
__global__ __launch_bounds__(512, 2)
void gru5(const bf16_t* __restrict__ A1, int lda1, int k1s,
          const bf16_t* __restrict__ Wih, int ldwih,
          const bf16_t* __restrict__ Hb,
          const bf16_t* __restrict__ Whh,
          const float* __restrict__ Hin,
          const float* __restrict__ bih, const float* __restrict__ bhh,
          float* __restrict__ Hout, bf16_t* __restrict__ HoutB)
{
  __shared__ bf16_t aT[3][128 * 64];
  __shared__ bf16_t bT[3][96 * 64];
  const int tid = threadIdx.x, wv = tid >> 6, lane = tid & 63;
  // bijective chunked XCD swizzle: grid 256, consecutive bids round-robin XCDs;
  // XCD x owns wg in [32x, 32x+32) = j-blocks [8x,8x+8) x all 4 m-blocks.
  const int bid = blockIdx.x;
  const int wg  = (bid & 7) * 32 + (bid >> 3);
  const int j0  = (wg >> 2) * 32;       // 0..2016
  const int m0  = (wg & 3) * 128;       // 0..384
  const int lr = lane & 15, lk = lane >> 4;
  const int rl = lane >> 3;             // 0..7
  const int cl = (lane & 7) * 8;

  fx4 acc[2][4];   // [mfrag][slot]
#pragma unroll
  for (int m = 0; m < 2; ++m)
#pragma unroll
    for (int g = 0; g < 4; ++g) acc[m][g] = fx4{0.f, 0.f, 0.f, 0.f};

  const bf16_t* A1b = A1 ? A1 : Hb;

  // ---- staging offsets (role split) ----
  int sOff0[4], sOff1[4], sSlot[4];
  if (wv < 4) {          // A producer: 16 row-groups of 8, 4 per wave
#pragma unroll
    for (int i = 0; i < 4; ++i) {
      const int t = wv * 4 + i;          // 0..15
      const int r = t * 8 + rl;          // 0..127
      const int c = cl ^ ((r & 7) * 8);
      sOff0[i] = (m0 + r) * lda1 + c;
      sOff1[i] = (m0 + r) * HD + c;
      sSlot[i] = t * 512;
    }
  } else {               // B producer: 12 row-groups of 8, 3 per wave
#pragma unroll
    for (int i = 0; i < 3; ++i) {
      const int t = (wv - 4) * 3 + i;    // 0..11
      const int r = t * 8 + rl;          // 0..95
      const int g = r >> 5, jj = r & 31;
      const int c = cl ^ ((r & 7) * 8);
      sOff0[i] = (g * HD + j0 + jj) * ldwih + c;
      sOff1[i] = (g * HD + j0 + jj) * HD + c;
      sSlot[i] = t * 512;
    }
    sOff0[3] = sOff1[3] = sSlot[3] = 0;
  }

  // ---- fragment read offsets (swizzled) ----
  int aRow[2], bRow[3], ko[2];
#pragma unroll
  for (int m = 0; m < 2; ++m) aRow[m] = ((wv & 3) * 32 + m * 16 + lr) * 64;
#pragma unroll
  for (int g = 0; g < 3; ++g) bRow[g] = (g * 32 + (wv >> 2) * 16 + lr) * 64;
#pragma unroll
  for (int h = 0; h < 2; ++h) ko[h] = (h * 32 + lk * 8) ^ ((lr & 7) * 8);

  auto stage = [&](int buf, int s) {
    const bool p = (s >= k1s);
    const int kb = (p ? (s - k1s) : s) * 64;
    if (wv < 4) {
      const bf16_t* src = p ? Hb : A1b;
      bf16_t* dst = &aT[buf][0];
#pragma unroll
      for (int i = 0; i < 4; ++i) gload16(src + (p ? sOff1[i] : sOff0[i]) + kb, dst + sSlot[i]);
    } else {
      const bf16_t* src = p ? Whh : Wih;
      bf16_t* dst = &bT[buf][0];
#pragma unroll
      for (int i = 0; i < 3; ++i) gload16(src + (p ? sOff1[i] : sOff0[i]) + kb, dst + sSlot[i]);
    }
  };

  const int nk = k1s + HD / 64;          // <= 41
  stage(0, 0); stage(1, 1); stage(2, 2);
  int buf = 0;
  for (int s = 0; s < nk; ++s) {
    const int rem = nk - 1 - s;
    if (rem >= 2)      { if (wv < 4) wait_vm8(); else wait_vm6(); }
    else if (rem == 1) { if (wv < 4) wait_vm4(); else wait_vm3(); }
    else               wait_vm0();
    __builtin_amdgcn_s_barrier();        // tile s fully resident
    const bf16_t* aB = &aT[buf][0];
    const bf16_t* bB = &bT[buf][0];
    bfx8 af[2][2], bfr[3][2];
#pragma unroll
    for (int m = 0; m < 2; ++m)
#pragma unroll
      for (int h = 0; h < 2; ++h)
        af[m][h] = *reinterpret_cast<const bfx8*>(&aB[aRow[m] + ko[h]]);
#pragma unroll
    for (int g = 0; g < 3; ++g)
#pragma unroll
      for (int h = 0; h < 2; ++h)
        bfr[g][h] = *reinterpret_cast<const bfx8*>(&bB[bRow[g] + ko[h]]);
    wait_lgkm0();
    __builtin_amdgcn_sched_barrier(0);
    __builtin_amdgcn_s_barrier();        // all waves done reading buf
    if (s + 3 < nk) stage(buf, s + 3);
    const bool p = (s >= k1s);
    __builtin_amdgcn_s_setprio(1);
#pragma unroll
    for (int h = 0; h < 2; ++h)
#pragma unroll
      for (int g = 0; g < 3; ++g) {
        const int slot = (g == 2) ? (p ? 3 : 2) : g;
#pragma unroll
        for (int m = 0; m < 2; ++m)
          acc[m][slot] = __builtin_amdgcn_mfma_f32_16x16x32_bf16(af[m][h], bfr[g][h], acc[m][slot], 0, 0, 0);
      }
    __builtin_amdgcn_s_setprio(0);
    buf = (buf == 2) ? 0 : buf + 1;
  }

  // ---- epilogue: gates + h update (wave: 32 rows x 16 cols) ----
  const int col = j0 + (wv >> 2) * 16 + lr;
  const float br  = bih[col] + bhh[col];
  const float bz  = bih[HD + col] + bhh[HD + col];
  const float bin = bih[2 * HD + col];
  const float bhn = bhh[2 * HD + col];
#pragma unroll
  for (int m = 0; m < 2; ++m) {
    const int rbase = m0 + (wv & 3) * 32 + m * 16 + lk * 4;
#pragma unroll
    for (int q = 0; q < 4; ++q) {
      const int row = rbase + q;
      const float r = sigmoidf_(acc[m][0][q] + br);
      const float z = sigmoidf_(acc[m][1][q] + bz);
      const float n = tanhf(acc[m][2][q] + bin + r * (acc[m][3][q] + bhn));
      const float hv = (1.0f - z) * n + z * Hin[(size_t)row * HD + col];
      Hout[(size_t)row * HD + col]  = hv;
      HoutB[(size_t)row * HD + col] = f2b(hv);
    }
  }
}

// ---------------- bf16 NT GEMM (counted-vmcnt pipeline, depth-2) ----------------
__global__ __launch_bounds__(256, 2)
void gemm_nt3(const bf16_t* __restrict__ A, int lda, int K,
              const bf16_t* __restrict__ W, int ldw,
              const float* __restrict__ bias,
              float* __restrict__ O, int ldo, int N,
              bf16_t* __restrict__ OB, int ldob)
{
  __shared__ bf16_t aT[2][64 * 64];
  __shared__ bf16_t bT[2][64 * 64];
  const int tid = threadIdx.x, wave = tid >> 6, lane = tid & 63;
  const int m0 = blockIdx.y * 64, n0 = blockIdx.x * 64;
  const int wm = wave & 1, wn = wave >> 1;
  const int lr = lane & 15, lk = lane >> 4;
  const int rl = lane >> 3, cl = (lane & 7) * 8;

  fx4 acc[2][2];
#pragma unroll
  for (int a = 0; a < 2; ++a)
#pragma unroll
    for (int b = 0; b < 2; ++b) acc[a][b] = fx4{0.f, 0.f, 0.f, 0.f};

  const bf16_t* pA[2]; const bf16_t* pB[2]; int slot[2];
#pragma unroll
  for (int i = 0; i < 2; ++i) {
    const int t = wave * 2 + i;
    const int r = t * 8 + rl;
    const int c = cl ^ ((r & 7) * 8);
    pA[i] = A + (size_t)(m0 + r) * lda + c;
    pB[i] = W + (size_t)(n0 + r) * ldw + c;
    slot[i] = t * 512;
  }
  int aRow[2], bRow[2], ko[2];
#pragma unroll
  for (int f = 0; f < 2; ++f) {
    aRow[f] = (wm * 32 + f * 16 + lr) * 64;
    bRow[f] = (wn * 32 + f * 16 + lr) * 64;
  }
#pragma unroll
  for (int h = 0; h < 2; ++h) ko[h] = (h * 32 + lk * 8) ^ ((lr & 7) * 8);

  auto stage = [&](int buf, int kb) {
#pragma unroll
    for (int i = 0; i < 2; ++i) {
      gload16(pA[i] + kb, &aT[buf][slot[i]]);
      gload16(pB[i] + kb, &bT[buf][slot[i]]);
    }
  };

  const int nk = K >> 6;
  stage(0, 0);
  stage(1, 64);
  for (int s = 0; s < nk; ++s) {
    if (s == nk - 1) wait_vm0(); else wait_vm4();
    __builtin_amdgcn_s_barrier();
    const bf16_t* aB = &aT[s & 1][0];
    const bf16_t* bB = &bT[s & 1][0];
    bfx8 af[2][2], bfr[2][2];
#pragma unroll
    for (int f = 0; f < 2; ++f)
#pragma unroll
      for (int h = 0; h < 2; ++h) {
        af[f][h]  = *reinterpret_cast<const bfx8*>(&aB[aRow[f] + ko[h]]);
        bfr[f][h] = *reinterpret_cast<const bfx8*>(&bB[bRow[f] + ko[h]]);
      }
    wait_lgkm0();
    __builtin_amdgcn_sched_barrier(0);
    __builtin_amdgcn_s_barrier();
    if (s + 2 < nk) stage(s & 1, (s + 2) << 6);
    __builtin_amdgcn_s_setprio(1);
#pragma unroll
    for (int h = 0; h < 2; ++h)
#pragma unroll
      for (int fm = 0; fm < 2; ++fm)
#pragma unroll
        for (int fj = 0; fj < 2; ++fj)
          acc[fm][fj] = __builtin_amdgcn_mfma_f32_16x16x32_bf16(af[fm][h], bfr[fj][h], acc[fm][fj], 0, 0, 0);
    __builtin_amdgcn_s_setprio(0);
  }

#pragma unroll
  for (int fm = 0; fm < 2; ++fm)
#pragma unroll
    for (int fj = 0; fj < 2; ++fj) {
      const int col = n0 + wn * 32 + fj * 16 + lr;
      if (col < N) {
        const float bb = bias[col];
#pragma unroll
        for (int q = 0; q < 4; ++q) {
          const int row = m0 + wm * 32 + fm * 16 + lk * 4 + q;
          const float v = acc[fm][fj][q] + bb;
          O[(size_t)row * ldo + col] = v;
          if (OB) OB[(size_t)row * ldob + col] = f2b(v);
        }
      }
    }
}

// ---------------- z build (writes bf16) ----------------
__global__ void build_zb(const float* __restrict__ mu, const float* __restrict__ lv,
                         const float* __restrict__ eps, const float* __restrict__ genre,
                         bf16_t* __restrict__ zb) {
  int i = blockIdx.x * 256 + threadIdx.x;
  int b = i >> 10, c = i & 1023;
  float v;
  if (c < LATM) {
    size_t k = (size_t)b * LATM + c;
    v = mu[k] + expf(0.5f * lv[k]) * eps[k];
  } else {
    v = genre[b * NGENRE + (c - LATM)];
  }
  zb[i] = f2b(v);
}

// ================= fp32 fallback =================
__global__ __launch_bounds__(256, 1)
void gru_stepF(const float* __restrict__ A1, int lda1, int K1,
               const float* __restrict__ Wih,
               const float* __restrict__ Hin,
               const float* __restrict__ Whh,
               const float* __restrict__ bih, const float* __restrict__ bhh,
               float* __restrict__ Hout)
{
  __shared__ bf16_t a_lds[128][32];
  __shared__ bf16_t b_lds[96][32];
  const int tid = threadIdx.x, wave = tid >> 6, lane = tid & 63;
  const int m0 = (blockIdx.x >> 6) * 128, j0 = (blockIdx.x & 63) * 32;
  const int lr = lane & 15, lk = lane >> 4;
  fx4 acc[2][2][4];
#pragma unroll
  for (int a = 0; a < 2; ++a)
#pragma unroll
    for (int b = 0; b < 2; ++b)
#pragma unroll
      for (int g = 0; g < 4; ++g) acc[a][b][g] = fx4{0.f, 0.f, 0.f, 0.f};

  for (int ph = 0; ph < 2; ++ph) {
    const float* Ag = ph ? Hin : A1;
    const int lda = ph ? HD : lda1, kLen = ph ? HD : K1;
    const float* W = ph ? Whh : Wih;
    const int nslot = ph ? 3 : 2;
    const int nkk = (kLen + 31) >> 5;
    for (int s = 0; s < nkk; ++s) {
      const int kb = s << 5;
#pragma unroll
      for (int it = 0; it < 16; ++it) {
        int i = tid + it * 256;
        int r = i >> 5, kk = i & 31, gk = kb + kk;
        float v = 0.0f;
        if (Ag && gk < kLen) v = Ag[(size_t)(m0 + r) * lda + gk];
        a_lds[r][kk] = f2b(v);
      }
#pragma unroll
      for (int it = 0; it < 12; ++it) {
        int i = tid + it * 256;
        int r = i >> 5, kk = i & 31, g = r >> 5, jj = r & 31, gk = kb + kk;
        b_lds[r][kk] = (gk < kLen) ? f2b(W[(size_t)(g * HD + j0 + jj) * kLen + gk]) : f2b(0.0f);
      }
      __syncthreads();
      bfx8 af[2];
#pragma unroll
      for (int fm = 0; fm < 2; ++fm)
        af[fm] = *reinterpret_cast<const bfx8*>(&a_lds[wave * 32 + fm * 16 + lr][lk * 8]);
#pragma unroll
      for (int g = 0; g < 3; ++g) {
        const int slot = (g == 2) ? nslot : g;
#pragma unroll
        for (int fj = 0; fj < 2; ++fj) {
          bfx8 bfr = *reinterpret_cast<const bfx8*>(&b_lds[g * 32 + fj * 16 + lr][lk * 8]);
#pragma unroll
          for (int fm = 0; fm < 2; ++fm)
            acc[fm][fj][slot] = __builtin_amdgcn_mfma_f32_16x16x32_bf16(af[fm], bfr, acc[fm][fj][slot], 0, 0, 0);
        }
      }
      __syncthreads();
    }
  }
#pragma unroll
  for (int fj = 0; fj < 2; ++fj) {
    const int col = j0 + fj * 16 + lr;
    const float br = bih[col] + bhh[col];
    const float bz = bih[HD + col] + bhh[HD + col];
    const float bin = bih[2 * HD + col];
    const float bhn = bhh[2 * HD + col];
#pragma unroll
    for (int fm = 0; fm < 2; ++fm) {
      const int rbase = m0 + wave * 32 + fm * 16 + lk * 4;
#pragma unroll
      for (int q = 0; q < 4; ++q) {
        const int row = rbase + q;
        const float r = sigmoidf_(acc[fm][fj][0][q] + br);
        const float z = sigmoidf_(acc[fm][fj][1][q] + bz);
        const float n = tanhf(acc[fm][fj][2][q] + bin + r * (acc[fm][fj][3][q] + bhn));
        Hout[(size_t)row * HD + col] = (1.0f - z) * n + z * Hin[(size_t)row * HD + col];
      }
    }
  }
}

__global__ __launch_bounds__(256, 1)
void gemm_ntF(const float* __restrict__ A, int lda, int K,
              const float* __restrict__ W,
              const float* __restrict__ bias,
              float* __restrict__ O, int ldo, int N)
{
  __shared__ bf16_t a_lds[64][32];
  __shared__ bf16_t b_lds[64][32];
  const int tid = threadIdx.x, wave = tid >> 6, lane = tid & 63;
  const int m0 = blockIdx.y * 64, n0 = blockIdx.x * 64;
  const int wm = (wave & 1) * 32, wn = (wave >> 1) * 32;
  const int lr = lane & 15, lk = lane >> 4;
  fx4 acc[2][2];
#pragma unroll
  for (int a = 0; a < 2; ++a)
#pragma unroll
    for (int b = 0; b < 2; ++b) acc[a][b] = fx4{0.f, 0.f, 0.f, 0.f};
  for (int kb = 0; kb < K; kb += 32) {
#pragma unroll
    for (int it = 0; it < 8; ++it) {
      int i = tid + it * 256;
      int r = i >> 5, kk = i & 31;
      a_lds[r][kk] = f2b(A[(size_t)(m0 + r) * lda + kb + kk]);
    }
#pragma unroll
    for (int it = 0; it < 8; ++it) {
      int i = tid + it * 256;
      int r = i >> 5, kk = i & 31;
      int n = n0 + r;
      b_lds[r][kk] = (n < N) ? f2b(W[(size_t)n * K + kb + kk]) : f2b(0.0f);
    }
    __syncthreads();
    bfx8 af[2], bfr[2];
#pragma unroll
    for (int f = 0; f < 2; ++f) {
      af[f] = *reinterpret_cast<const bfx8*>(&a_lds[wm + f * 16 + lr][lk * 8]);
      bfr[f] = *reinterpret_cast<const bfx8*>(&b_lds[wn + f * 16 + lr][lk * 8]);
    }
#pragma unroll
    for (int fm = 0; fm < 2; ++fm)
#pragma unroll
      for (int fj = 0; fj < 2; ++fj)
        acc[fm][fj] = __builtin_amdgcn_mfma_f32_16x16x32_bf16(af[fm], bfr[fj], acc[fm][fj], 0, 0, 0);
    __syncthreads();
  }
#pragma unroll
  for (int fm = 0; fm < 2; ++fm)
#pragma unroll
    for (int fj = 0; fj < 2; ++fj) {
      const int col = n0 + wn + fj * 16 + lr;
      if (col < N) {
        const float bb = bias[col];
#pragma unroll
        for (int q = 0; q < 4; ++q) {
          const int row = m0 + wm + fm * 16 + lk * 4 + q;
          O[(size_t)row * ldo + col] = acc[fm][fj][q] + bb;
        }
      }
    }
}

__global__ void build_zf(const float* __restrict__ mu, const float* __restrict__ lv,
                         const float* __restrict__ eps, const float* __restrict__ genre,
                         float* __restrict__ z) {
  int i = blockIdx.x * 256 + threadIdx.x;
  int b = i >> 10, c = i & 1023;
  z[i] = (c < LATM) ? mu[(size_t)b * LATM + c] + expf(0.5f * lv[(size_t)b * LATM + c]) * eps[(size_t)b * LATM + c]
                    : genre[b * NGENRE + (c - LATM)];
}

// ---------------- host ----------------
extern "C" void kernel_launch(void* const* d_in, const int* in_sizes, int n_in,
                              void* d_out, int out_size, void* d_ws, size_t ws_size,
                              hipStream_t stream) {
  const float* x      = (const float*)d_in[0];
  const float* genre  = (const float*)d_in[1];
  const float* eps    = (const float*)d_in[2];
  const float* eWih   = (const float*)d_in[3];
  const float* eWhh   = (const float*)d_in[4];
  const float* eBih   = (const float*)d_in[5];
  const float* eBhh   = (const float*)d_in[6];
  const float* dWih   = (const float*)d_in[7];
  const float* dWhh   = (const float*)d_in[8];
  const float* dBih   = (const float*)d_in[9];
  const float* dBhh   = (const float*)d_in[10];
  const float* fcMuW  = (const float*)d_in[11];
  const float* fcMuB  = (const float*)d_in[12];
  const float* fcLvW  = (const float*)d_in[13];
  const float* fcLvB  = (const float*)d_in[14];
  const float* fcOutW = (const float*)d_in[15];
  const float* fcOutB = (const float*)d_in[16];
  const float* fcDecW = (const float*)d_in[17];
  const float* fcDecB = (const float*)d_in[18];

  float* out = (float*)d_out;
  float* muO = out + (size_t)TT * BB * INDIM;
  float* lvO = muO + (size_t)BB * LATM;

  const size_t nEih = (size_t)3 * HD * XKP;
  const size_t nEhh = (size_t)3 * HD * HD;
  const size_t nDih = (size_t)3 * HD * INDIM;
  const size_t nDhh = (size_t)3 * HD * HD;
  const size_t nMu  = (size_t)1024 * HD;
  const size_t nOut = (size_t)HD * LATD;
  const size_t nDec = (size_t)INDIM * HD;
  const size_t oEih = 0;
  const size_t oEhh = oEih + nEih;
  const size_t oDih = oEhh + nEhh;
  const size_t oDhh = oDih + nDih;
  const size_t oMu  = oDhh + nDhh;
  const size_t oLv  = oMu + nMu;
  const size_t oOut = oLv + nMu;
  const size_t oDec = oOut + nOut;
  const size_t wTot = oDec + nDec;

  const size_t bytesW  = wTot * 2;
  const size_t bytesHF = (size_t)BB * HD * 4;
  const size_t bytesHB = (size_t)BB * HD * 2;
  const size_t bytesZB = (size_t)BB * LATD * 2;
  const size_t bytesNB = (size_t)BB * INDIM * 2;
  const size_t bytesX1 = (size_t)BB * XKP * 2;
  const size_t bytesXB = (size_t)TT * BB * XKP * 2;
  const size_t needB = bytesW + 2 * bytesHF + 2 * bytesHB + bytesZB + bytesNB + bytesX1 + 1024;
  const size_t needA = needB + bytesXB;

  if (ws_size >= needB) {
    const bool haveXB = (ws_size >= needA);
    char* p = (char*)d_ws;
    bf16_t* wb = (bf16_t*)p;            p += bytesW;
    float* h0  = (float*)p;             p += bytesHF;
    float* h1  = (float*)p;             p += bytesHF;
    bf16_t* hb0 = (bf16_t*)p;           p += bytesHB;
    bf16_t* hb1 = (bf16_t*)p;           p += bytesHB;
    bf16_t* zb  = (bf16_t*)p;           p += bytesZB;
    bf16_t* nb  = (bf16_t*)p;           p += bytesNB;
    bf16_t* x1  = (bf16_t*)p;           p += bytesX1;
    bf16_t* xb  = haveXB ? (bf16_t*)p : nullptr;

    auto cast = [&](const float* s, bf16_t* d, int rs, int rp, int K, int ldp) {
      int g = rp > 8192 ? 8192 : rp;
      wcast_pad<<<g, 256, 0, stream>>>(s, d, rs, rp, K, ldp);
    };
    cast(eWih,   wb + oEih, 3 * HD, 3 * HD, XK,    XKP);
    cast(eWhh,   wb + oEhh, 3 * HD, 3 * HD, HD,    HD);
    cast(dWih,   wb + oDih, 3 * HD, 3 * HD, INDIM, INDIM);
    cast(dWhh,   wb + oDhh, 3 * HD, 3 * HD, HD,    HD);
    cast(fcMuW,  wb + oMu,  LATM,   1024,   HD,    HD);
    cast(fcLvW,  wb + oLv,  LATM,   1024,   HD,    HD);
    cast(fcOutW, wb + oOut, HD,     HD,     LATD,  LATD);
    cast(fcDecW, wb + oDec, INDIM,  INDIM,  HD,    HD);
    if (haveXB) cast(x, xb, TT * BB, TT * BB, XK, XKP);

    hipMemsetAsync(h0, 0, bytesHF, stream);
    hipMemsetAsync(hb0, 0, bytesHB, stream);

    float*  hF[2] = {h0, h1};
    bf16_t* hB[2] = {hb0, hb1};

    // ---- encoder ----
    for (int t = 0; t < TT; ++t) {
      const int ci = t & 1, co = ci ^ 1;
      const bf16_t* xt;
      if (haveXB) {
        xt = xb + (size_t)t * BB * XKP;
      } else {
        wcast_pad<<<512, 256, 0, stream>>>(x + (size_t)t * BB * XK, x1, BB, BB, XK, XKP);
        xt = x1;
      }
      gru5<<<256, 512, 0, stream>>>(xt, XKP, XKP / 64,
                                    wb + oEih, XKP, hB[ci], wb + oEhh,
                                    hF[ci], eBih, eBhh, hF[co], hB[co]);
    }
    // h_enc = hF[0]/hB[0]
    gemm_nt3<<<dim3(16, 8), 256, 0, stream>>>(hB[0], HD, HD, wb + oMu, HD, fcMuB,
                                              muO, LATM, LATM, nullptr, 0);
    gemm_nt3<<<dim3(16, 8), 256, 0, stream>>>(hB[0], HD, HD, wb + oLv, HD, fcLvB,
                                              lvO, LATM, LATM, nullptr, 0);
    build_zb<<<(BB * LATD) / 256, 256, 0, stream>>>(muO, lvO, eps, genre, zb);
    gemm_nt3<<<dim3(32, 8), 256, 0, stream>>>(zb, LATD, LATD, wb + oOut, LATD, fcOutB,
                                              hF[0], HD, HD, hB[0], HD);
    // ---- decoder ----
    for (int t = 0; t < TT; ++t) {
      const int ci = t & 1, co = ci ^ 1;
      gru5<<<256, 512, 0, stream>>>(t ? nb : (const bf16_t*)nullptr, INDIM,
                                    t ? INDIM / 64 : 0,
                                    wb + oDih, INDIM, hB[ci], wb + oDhh,
                                    hF[ci], dBih, dBhh, hF[co], hB[co]);
      gemm_nt3<<<dim3(8, 8), 256, 0, stream>>>(hB[co], HD, HD, wb + oDec, HD, fcDecB,
                                               out + (size_t)t * BB * INDIM, INDIM, INDIM,
                                               nb, INDIM);
    }
  } else {
    // ---- fp32 fallback ----
    float* h0 = (float*)d_ws;
    float* h1 = h0 + (size_t)BB * HD;
    float* zb = h1 + (size_t)BB * HD;
    hipMemsetAsync(h0, 0, (size_t)BB * HD * sizeof(float), stream);
    float* hF[2] = {h0, h1};
    for (int t = 0; t < TT; ++t) {
      const int ci = t & 1, co = ci ^ 1;
      gru_stepF<<<256, 256, 0, stream>>>(x + (size_t)t * BB * XK, XK, XK, eWih,
                                         hF[ci], eWhh, eBih, eBhh, hF[co]);
    }
    gemm_ntF<<<dim3(16, 8), 256, 0, stream>>>(hF[0], HD, HD, fcMuW, fcMuB, muO, LATM, LATM);
    gemm_ntF<<<dim3(16, 8), 256, 0, stream>>>(hF[0], HD, HD, fcLvW, fcLvB, lvO, LATM, LATM);
    build_zf<<<(BB * LATD) / 256, 256, 0, stream>>>(muO, lvO, eps, genre, zb);
    gemm_ntF<<<dim3(32, 8), 256, 0, stream>>>(zb, LATD, LATD, fcOutW, fcOutB, hF[0], HD, HD);
    for (int t = 0; t < TT; ++t) {
      const int ci = t & 1, co = ci ^ 1;
      gru_stepF<<<256, 256, 0, stream>>>(t ? out + (size_t)(t - 1) * BB * INDIM : nullptr,
                                         INDIM, INDIM, dWih, hF[ci], dWhh, dBih, dBhh, hF[co]);
      gemm_ntF<<<dim3(8, 8), 256, 0, stream>>>(hF[co], HD, HD, fcDecW, fcDecB,
                                               out + (size_t)t * BB * INDIM, INDIM, INDIM);
    }
  }
  (void)in_sizes; (void)n_in; (void)out_size;
}

// Round 7
// 21411.583 us; speedup vs baseline: 1.5867x; 1.5867x over previous
//
#include <hip/hip_runtime.h>
#include <hip/hip_bf16.h>

typedef __bf16 bf16_t;
typedef bf16_t bfx8 __attribute__((ext_vector_type(8)));
typedef float  fx4  __attribute__((ext_vector_type(4)));

#define TT     256
#define BB     512
#define INDIM  512
#define NGENRE 5
#define HD     2048
#define LATD   1024
#define LATM   1019
#define XK     517
#define XKP    576

// ---------------- helpers ----------------
__device__ __forceinline__ bf16_t f2b(float f) {
  unsigned u = __builtin_bit_cast(unsigned, f);
  u += 0x7fffu + ((u >> 16) & 1u);
  unsigned short s = (unsigned short)(u >> 16);
  return __builtin_bit_cast(bf16_t, s);
}
__device__ __forceinline__ float sigmoidf_(float x) { return 1.0f / (1.0f + __expf(-x)); }

__device__ __forceinline__ void gload16(const bf16_t* g, bf16_t* l) {
  __builtin_amdgcn_global_load_lds((const __attribute__((address_space(1))) void*)g,
                                   (__attribute__((address_space(3))) void*)l,
                                   16, 0, 0);
}
__device__ __forceinline__ void wait_vm0()  { asm volatile("s_waitcnt vmcnt(0)" ::: "memory"); }
__device__ __forceinline__ void wait_vm4()  { asm volatile("s_waitcnt vmcnt(4)" ::: "memory"); }
__device__ __forceinline__ void wait_vm5()  { asm volatile("s_waitcnt vmcnt(5)" ::: "memory"); }
__device__ __forceinline__ void wait_vm10() { asm volatile("s_waitcnt vmcnt(10)" ::: "memory"); }
__device__ __forceinline__ void wait_lgkm0() { asm volatile("s_waitcnt lgkmcnt(0)" ::: "memory"); }

// ---------------- fp32 -> bf16 cast with row/col zero-padding ----------------
__global__ void wcast_pad(const float* __restrict__ src, bf16_t* __restrict__ dst,
                          int rows_src, int rows_pad, int K, int ldp) {
  for (int r = blockIdx.x; r < rows_pad; r += gridDim.x)
    for (int c = threadIdx.x; c < ldp; c += 256)
      dst[(size_t)r * ldp + c] = (r < rows_src && c < K) ? f2b(src[(size_t)r * K + c]) : f2b(0.0f);
}

// ---------------- fused GRU step v3c: round-3 kernel + XCD j-ownership + depth-3 ----
// Block: 64 rows x 32 j-cols (x3 gates), 256 thr (4 waves), grid 512.
// XCD x owns j-blocks [8x,8x+8) x all 8 m-blocks -> per-XCD B working set ~3.9MB (L2-fit).
// 5 gload16/wave/stage, depth-3 => waits vmcnt(10)/(5)/(0). LDS 3x20KB=60KB (2 blocks/CU).
// acc slots: 0=r 1=z 2=inn(phase0) 3=hn(phase1)
__global__ __launch_bounds__(256, 2)
void gru3(const bf16_t* __restrict__ A1, int lda1, int k1s,
          const bf16_t* __restrict__ Wih, int ldwih,
          const bf16_t* __restrict__ Hb,
          const bf16_t* __restrict__ Whh,
          const float* __restrict__ Hin,
          const float* __restrict__ bih, const float* __restrict__ bhh,
          float* __restrict__ Hout, bf16_t* __restrict__ HoutB)
{
  __shared__ bf16_t aT[3][64 * 64];
  __shared__ bf16_t bT[3][96 * 64];
  const int tid = threadIdx.x, wave = tid >> 6, lane = tid & 63;
  // XCD-ownership remap: xcd = bid&7 owns 64 consecutive logical wgs =
  // j-blocks [8*xcd, 8*xcd+8) x all 8 m-blocks (B panels L2-resident per XCD).
  const int bid = blockIdx.x;
  const int xcd = bid & 7, loc = bid >> 3;     // loc 0..63
  const int j0 = (xcd * 8 + (loc >> 3)) * 32;  // 0..2016
  const int m0 = (loc & 7) * 64;               // 0..448
  const int lr = lane & 15, lk = lane >> 4;
  const int rl = lane >> 3;          // 0..7
  const int cl = (lane & 7) * 8;     // element chunk

  fx4 acc[2][4];
#pragma unroll
  for (int b = 0; b < 2; ++b)
#pragma unroll
    for (int g = 0; g < 4; ++g) acc[b][g] = fx4{0.f, 0.f, 0.f, 0.f};

  // staging source pointers (global col pre-swizzled; LDS dest linear)
  const bf16_t* A1b = A1 ? A1 : Hb;
  const bf16_t* pA0[2]; const bf16_t* pA1[2]; int aSlot[2];
#pragma unroll
  for (int i = 0; i < 2; ++i) {
    const int t = wave * 2 + i;
    const int r = t * 8 + rl;                  // 0..63
    const int c = cl ^ ((r & 7) * 8);
    pA0[i] = A1b + (size_t)(m0 + r) * lda1 + c;
    pA1[i] = Hb  + (size_t)(m0 + r) * HD   + c;
    aSlot[i] = t * 512;
  }
  const bf16_t* pB0[3]; const bf16_t* pB1[3]; int bSlot[3];
#pragma unroll
  for (int i = 0; i < 3; ++i) {
    const int t = wave * 3 + i;
    const int r = t * 8 + rl;                  // 0..95
    const int g = r >> 5, jj = r & 31;
    const int c = cl ^ ((r & 7) * 8);
    pB0[i] = Wih + (size_t)(g * HD + j0 + jj) * ldwih + c;
    pB1[i] = Whh + (size_t)(g * HD + j0 + jj) * HD    + c;
    bSlot[i] = t * 512;
  }
  // fragment read offsets (swizzled)
  int aRow, bRow[3][2], ko[2];
  aRow = (wave * 16 + lr) * 64;
#pragma unroll
  for (int g = 0; g < 3; ++g)
#pragma unroll
    for (int fj = 0; fj < 2; ++fj) bRow[g][fj] = (g * 32 + fj * 16 + lr) * 64;
#pragma unroll
  for (int h = 0; h < 2; ++h) ko[h] = (h * 32 + lk * 8) ^ ((lr & 7) * 8);

  auto stage = [&](int buf, int s) {
    const int p  = (s >= k1s);
    const int kb = (p ? (s - k1s) : s) * 64;
    if (p) {
#pragma unroll
      for (int i = 0; i < 2; ++i) gload16(pA1[i] + kb, &aT[buf][aSlot[i]]);
#pragma unroll
      for (int i = 0; i < 3; ++i) gload16(pB1[i] + kb, &bT[buf][bSlot[i]]);
    } else {
#pragma unroll
      for (int i = 0; i < 2; ++i) gload16(pA0[i] + kb, &aT[buf][aSlot[i]]);
#pragma unroll
      for (int i = 0; i < 3; ++i) gload16(pB0[i] + kb, &bT[buf][bSlot[i]]);
    }
  };

  const int nk = k1s + HD / 64;
  stage(0, 0); stage(1, 1); stage(2, 2);
  int buf = 0;
  for (int s = 0; s < nk; ++s) {
    const int rem = nk - 1 - s;
    if (rem >= 2) wait_vm10();
    else if (rem == 1) wait_vm5();
    else wait_vm0();
    __builtin_amdgcn_s_barrier();            // tile s fully in LDS (all waves)
    const bf16_t* aB = &aT[buf][0];
    const bf16_t* bB = &bT[buf][0];
    bfx8 af[2]; bfx8 bfr[3][2][2];
#pragma unroll
    for (int h = 0; h < 2; ++h)
      af[h] = *reinterpret_cast<const bfx8*>(&aB[aRow + ko[h]]);
#pragma unroll
    for (int g = 0; g < 3; ++g)
#pragma unroll
      for (int fj = 0; fj < 2; ++fj)
#pragma unroll
        for (int h = 0; h < 2; ++h)
          bfr[g][fj][h] = *reinterpret_cast<const bfx8*>(&bB[bRow[g][fj] + ko[h]]);
    wait_lgkm0();
    __builtin_amdgcn_sched_barrier(0);
    __builtin_amdgcn_s_barrier();            // all waves done reading buf
    if (s + 3 < nk) stage(buf, s + 3);       // refill freed buffer
    const int p = (s >= k1s);
    __builtin_amdgcn_s_setprio(1);
#pragma unroll
    for (int h = 0; h < 2; ++h)
#pragma unroll
      for (int g = 0; g < 3; ++g) {
        const int slot = (g == 2) ? (p ? 3 : 2) : g;
#pragma unroll
        for (int fj = 0; fj < 2; ++fj)
          acc[fj][slot] = __builtin_amdgcn_mfma_f32_16x16x32_bf16(af[h], bfr[g][fj][h], acc[fj][slot], 0, 0, 0);
      }
    __builtin_amdgcn_s_setprio(0);
    buf = (buf == 2) ? 0 : buf + 1;
  }

  // ---- epilogue: gates + h update ----
#pragma unroll
  for (int fj = 0; fj < 2; ++fj) {
    const int col = j0 + fj * 16 + lr;
    const float br  = bih[col] + bhh[col];
    const float bz  = bih[HD + col] + bhh[HD + col];
    const float bin = bih[2 * HD + col];
    const float bhn = bhh[2 * HD + col];
    const int rbase = m0 + wave * 16 + lk * 4;
#pragma unroll
    for (int q = 0; q < 4; ++q) {
      const int row = rbase + q;
      const float r = sigmoidf_(acc[fj][0][q] + br);
      const float z = sigmoidf_(acc[fj][1][q] + bz);
      const float n = tanhf(acc[fj][2][q] + bin + r * (acc[fj][3][q] + bhn));
      const float hv = (1.0f - z) * n + z * Hin[(size_t)row * HD + col];
      Hout[(size_t)row * HD + col]  = hv;
      HoutB[(size_t)row * HD + col] = f2b(hv);
    }
  }
}

// ---------------- bf16 NT GEMM (counted-vmcnt pipeline, depth-2) ----------------
__global__ __launch_bounds__(256, 2)
void gemm_nt3(const bf16_t* __restrict__ A, int lda, int K,
              const bf16_t* __restrict__ W, int ldw,
              const float* __restrict__ bias,
              float* __restrict__ O, int ldo, int N,
              bf16_t* __restrict__ OB, int ldob)
{
  __shared__ bf16_t aT[2][64 * 64];
  __shared__ bf16_t bT[2][64 * 64];
  const int tid = threadIdx.x, wave = tid >> 6, lane = tid & 63;
  const int m0 = blockIdx.y * 64, n0 = blockIdx.x * 64;
  const int wm = wave & 1, wn = wave >> 1;
  const int lr = lane & 15, lk = lane >> 4;
  const int rl = lane >> 3, cl = (lane & 7) * 8;

  fx4 acc[2][2];
#pragma unroll
  for (int a = 0; a < 2; ++a)
#pragma unroll
    for (int b = 0; b < 2; ++b) acc[a][b] = fx4{0.f, 0.f, 0.f, 0.f};

  const bf16_t* pA[2]; const bf16_t* pB[2]; int slot[2];
#pragma unroll
  for (int i = 0; i < 2; ++i) {
    const int t = wave * 2 + i;
    const int r = t * 8 + rl;
    const int c = cl ^ ((r & 7) * 8);
    pA[i] = A + (size_t)(m0 + r) * lda + c;
    pB[i] = W + (size_t)(n0 + r) * ldw + c;
    slot[i] = t * 512;
  }
  int aRow[2], bRow[2], ko[2];
#pragma unroll
  for (int f = 0; f < 2; ++f) {
    aRow[f] = (wm * 32 + f * 16 + lr) * 64;
    bRow[f] = (wn * 32 + f * 16 + lr) * 64;
  }
#pragma unroll
  for (int h = 0; h < 2; ++h) ko[h] = (h * 32 + lk * 8) ^ ((lr & 7) * 8);

  auto stage = [&](int buf, int kb) {
#pragma unroll
    for (int i = 0; i < 2; ++i) {
      gload16(pA[i] + kb, &aT[buf][slot[i]]);
      gload16(pB[i] + kb, &bT[buf][slot[i]]);
    }
  };

  const int nk = K >> 6;
  stage(0, 0);
  stage(1, 64);
  for (int s = 0; s < nk; ++s) {
    if (s == nk - 1) wait_vm0(); else wait_vm4();
    __builtin_amdgcn_s_barrier();
    const bf16_t* aB = &aT[s & 1][0];
    const bf16_t* bB = &bT[s & 1][0];
    bfx8 af[2][2], bfr[2][2];
#pragma unroll
    for (int f = 0; f < 2; ++f)
#pragma unroll
      for (int h = 0; h < 2; ++h) {
        af[f][h]  = *reinterpret_cast<const bfx8*>(&aB[aRow[f] + ko[h]]);
        bfr[f][h] = *reinterpret_cast<const bfx8*>(&bB[bRow[f] + ko[h]]);
      }
    wait_lgkm0();
    __builtin_amdgcn_sched_barrier(0);
    __builtin_amdgcn_s_barrier();
    if (s + 2 < nk) stage(s & 1, (s + 2) << 6);
    __builtin_amdgcn_s_setprio(1);
#pragma unroll
    for (int h = 0; h < 2; ++h)
#pragma unroll
      for (int fm = 0; fm < 2; ++fm)
#pragma unroll
        for (int fj = 0; fj < 2; ++fj)
          acc[fm][fj] = __builtin_amdgcn_mfma_f32_16x16x32_bf16(af[fm][h], bfr[fj][h], acc[fm][fj], 0, 0, 0);
    __builtin_amdgcn_s_setprio(0);
  }

#pragma unroll
  for (int fm = 0; fm < 2; ++fm)
#pragma unroll
    for (int fj = 0; fj < 2; ++fj) {
      const int col = n0 + wn * 32 + fj * 16 + lr;
      if (col < N) {
        const float bb = bias[col];
#pragma unroll
        for (int q = 0; q < 4; ++q) {
          const int row = m0 + wm * 32 + fm * 16 + lk * 4 + q;
          const float v = acc[fm][fj][q] + bb;
          O[(size_t)row * ldo + col] = v;
          if (OB) OB[(size_t)row * ldob + col] = f2b(v);
        }
      }
    }
}

// ---------------- z build (writes bf16) ----------------
__global__ void build_zb(const float* __restrict__ mu, const float* __restrict__ lv,
                         const float* __restrict__ eps, const float* __restrict__ genre,
                         bf16_t* __restrict__ zb) {
  int i = blockIdx.x * 256 + threadIdx.x;
  int b = i >> 10, c = i & 1023;
  float v;
  if (c < LATM) {
    size_t k = (size_t)b * LATM + c;
    v = mu[k] + expf(0.5f * lv[k]) * eps[k];
  } else {
    v = genre[b * NGENRE + (c - LATM)];
  }
  zb[i] = f2b(v);
}

// ================= fp32 fallback =================
__global__ __launch_bounds__(256, 1)
void gru_stepF(const float* __restrict__ A1, int lda1, int K1,
               const float* __restrict__ Wih,
               const float* __restrict__ Hin,
               const float* __restrict__ Whh,
               const float* __restrict__ bih, const float* __restrict__ bhh,
               float* __restrict__ Hout)
{
  __shared__ bf16_t a_lds[128][32];
  __shared__ bf16_t b_lds[96][32];
  const int tid = threadIdx.x, wave = tid >> 6, lane = tid & 63;
  const int m0 = (blockIdx.x >> 6) * 128, j0 = (blockIdx.x & 63) * 32;
  const int lr = lane & 15, lk = lane >> 4;
  fx4 acc[2][2][4];
#pragma unroll
  for (int a = 0; a < 2; ++a)
#pragma unroll
    for (int b = 0; b < 2; ++b)
#pragma unroll
      for (int g = 0; g < 4; ++g) acc[a][b][g] = fx4{0.f, 0.f, 0.f, 0.f};

  for (int ph = 0; ph < 2; ++ph) {
    const float* Ag = ph ? Hin : A1;
    const int lda = ph ? HD : lda1, kLen = ph ? HD : K1;
    const float* W = ph ? Whh : Wih;
    const int nslot = ph ? 3 : 2;
    const int nkk = (kLen + 31) >> 5;
    for (int s = 0; s < nkk; ++s) {
      const int kb = s << 5;
#pragma unroll
      for (int it = 0; it < 16; ++it) {
        int i = tid + it * 256;
        int r = i >> 5, kk = i & 31, gk = kb + kk;
        float v = 0.0f;
        if (Ag && gk < kLen) v = Ag[(size_t)(m0 + r) * lda + gk];
        a_lds[r][kk] = f2b(v);
      }
#pragma unroll
      for (int it = 0; it < 12; ++it) {
        int i = tid + it * 256;
        int r = i >> 5, kk = i & 31, g = r >> 5, jj = r & 31, gk = kb + kk;
        b_lds[r][kk] = (gk < kLen) ? f2b(W[(size_t)(g * HD + j0 + jj) * kLen + gk]) : f2b(0.0f);
      }
      __syncthreads();
      bfx8 af[2];
#pragma unroll
      for (int fm = 0; fm < 2; ++fm)
        af[fm] = *reinterpret_cast<const bfx8*>(&a_lds[wave * 32 + fm * 16 + lr][lk * 8]);
#pragma unroll
      for (int g = 0; g < 3; ++g) {
        const int slot = (g == 2) ? nslot : g;
#pragma unroll
        for (int fj = 0; fj < 2; ++fj) {
          bfx8 bfr = *reinterpret_cast<const bfx8*>(&b_lds[g * 32 + fj * 16 + lr][lk * 8]);
#pragma unroll
          for (int fm = 0; fm < 2; ++fm)
            acc[fm][fj][slot] = __builtin_amdgcn_mfma_f32_16x16x32_bf16(af[fm], bfr, acc[fm][fj][slot], 0, 0, 0);
        }
      }
      __syncthreads();
    }
  }
#pragma unroll
  for (int fj = 0; fj < 2; ++fj) {
    const int col = j0 + fj * 16 + lr;
    const float br = bih[col] + bhh[col];
    const float bz = bih[HD + col] + bhh[HD + col];
    const float bin = bih[2 * HD + col];
    const float bhn = bhh[2 * HD + col];
#pragma unroll
    for (int fm = 0; fm < 2; ++fm) {
      const int rbase = m0 + wave * 32 + fm * 16 + lk * 4;
#pragma unroll
      for (int q = 0; q < 4; ++q) {
        const int row = rbase + q;
        const float r = sigmoidf_(acc[fm][fj][0][q] + br);
        const float z = sigmoidf_(acc[fm][fj][1][q] + bz);
        const float n = tanhf(acc[fm][fj][2][q] + bin + r * (acc[fm][fj][3][q] + bhn));
        Hout[(size_t)row * HD + col] = (1.0f - z) * n + z * Hin[(size_t)row * HD + col];
      }
    }
  }
}

__global__ __launch_bounds__(256, 1)
void gemm_ntF(const float* __restrict__ A, int lda, int K,
              const float* __restrict__ W,
              const float* __restrict__ bias,
              float* __restrict__ O, int ldo, int N)
{
  __shared__ bf16_t a_lds[64][32];
  __shared__ bf16_t b_lds[64][32];
  const int tid = threadIdx.x, wave = tid >> 6, lane = tid & 63;
  const int m0 = blockIdx.y * 64, n0 = blockIdx.x * 64;
  const int wm = (wave & 1) * 32, wn = (wave >> 1) * 32;
  const int lr = lane & 15, lk = lane >> 4;
  fx4 acc[2][2];
#pragma unroll
  for (int a = 0; a < 2; ++a)
#pragma unroll
    for (int b = 0; b < 2; ++b) acc[a][b] = fx4{0.f, 0.f, 0.f, 0.f};
  for (int kb = 0; kb < K; kb += 32) {
#pragma unroll
    for (int it = 0; it < 8; ++it) {
      int i = tid + it * 256;
      int r = i >> 5, kk = i & 31;
      a_lds[r][kk] = f2b(A[(size_t)(m0 + r) * lda + kb + kk]);
    }
#pragma unroll
    for (int it = 0; it < 8; ++it) {
      int i = tid + it * 256;
      int r = i >> 5, kk = i & 31;
      int n = n0 + r;
      b_lds[r][kk] = (n < N) ? f2b(W[(size_t)n * K + kb + kk]) : f2b(0.0f);
    }
    __syncthreads();
    bfx8 af[2], bfr[2];
#pragma unroll
    for (int f = 0; f < 2; ++f) {
      af[f] = *reinterpret_cast<const bfx8*>(&a_lds[wm + f * 16 + lr][lk * 8]);
      bfr[f] = *reinterpret_cast<const bfx8*>(&b_lds[wn + f * 16 + lr][lk * 8]);
    }
#pragma unroll
    for (int fm = 0; fm < 2; ++fm)
#pragma unroll
      for (int fj = 0; fj < 2; ++fj)
        acc[fm][fj] = __builtin_amdgcn_mfma_f32_16x16x32_bf16(af[fm], bfr[fj], acc[fm][fj], 0, 0, 0);
    __syncthreads();
  }
#pragma unroll
  for (int fm = 0; fm < 2; ++fm)
#pragma unroll
    for (int fj = 0; fj < 2; ++fj) {
      const int col = n0 + wn + fj * 16 + lr;
      if (col < N) {
        const float bb = bias[col];
#pragma unroll
        for (int q = 0; q < 4; ++q) {
          const int row = m0 + wm + fm * 16 + lk * 4 + q;
          O[(size_t)row * ldo + col] = acc[fm][fj][q] + bb;
        }
      }
    }
}

__global__ void build_zf(const float* __restrict__ mu, const float* __restrict__ lv,
                         const float* __restrict__ eps, const float* __restrict__ genre,
                         float* __restrict__ z) {
  int i = blockIdx.x * 256 + threadIdx.x;
  int b = i >> 10, c = i & 1023;
  z[i] = (c < LATM) ? mu[(size_t)b * LATM + c] + expf(0.5f * lv[(size_t)b * LATM + c]) * eps[(size_t)b * LATM + c]
                    : genre[b * NGENRE + (c - LATM)];
}

// ---------------- host ----------------
extern "C" void kernel_launch(void* const* d_in, const int* in_sizes, int n_in,
                              void* d_out, int out_size, void* d_ws, size_t ws_size,
                              hipStream_t stream) {
  const float* x      = (const float*)d_in[0];
  const float* genre  = (const float*)d_in[1];
  const float* eps    = (const float*)d_in[2];
  const float* eWih   = (const float*)d_in[3];
  const float* eWhh   = (const float*)d_in[4];
  const float* eBih   = (const float*)d_in[5];
  const float* eBhh   = (const float*)d_in[6];
  const float* dWih   = (const float*)d_in[7];
  const float* dWhh   = (const float*)d_in[8];
  const float* dBih   = (const float*)d_in[9];
  const float* dBhh   = (const float*)d_in[10];
  const float* fcMuW  = (const float*)d_in[11];
  const float* fcMuB  = (const float*)d_in[12];
  const float* fcLvW  = (const float*)d_in[13];
  const float* fcLvB  = (const float*)d_in[14];
  const float* fcOutW = (const float*)d_in[15];
  const float* fcOutB = (const float*)d_in[16];
  const float* fcDecW = (const float*)d_in[17];
  const float* fcDecB = (const float*)d_in[18];

  float* out = (float*)d_out;
  float* muO = out + (size_t)TT * BB * INDIM;
  float* lvO = muO + (size_t)BB * LATM;

  const size_t nEih = (size_t)3 * HD * XKP;
  const size_t nEhh = (size_t)3 * HD * HD;
  const size_t nDih = (size_t)3 * HD * INDIM;
  const size_t nDhh = (size_t)3 * HD * HD;
  const size_t nMu  = (size_t)1024 * HD;
  const size_t nOut = (size_t)HD * LATD;
  const size_t nDec = (size_t)INDIM * HD;
  const size_t oEih = 0;
  const size_t oEhh = oEih + nEih;
  const size_t oDih = oEhh + nEhh;
  const size_t oDhh = oDih + nDih;
  const size_t oMu  = oDhh + nDhh;
  const size_t oLv  = oMu + nMu;
  const size_t oOut = oLv + nMu;
  const size_t oDec = oOut + nOut;
  const size_t wTot = oDec + nDec;

  const size_t bytesW  = wTot * 2;
  const size_t bytesHF = (size_t)BB * HD * 4;
  const size_t bytesHB = (size_t)BB * HD * 2;
  const size_t bytesZB = (size_t)BB * LATD * 2;
  const size_t bytesNB = (size_t)BB * INDIM * 2;
  const size_t bytesX1 = (size_t)BB * XKP * 2;
  const size_t bytesXB = (size_t)TT * BB * XKP * 2;
  const size_t needB = bytesW + 2 * bytesHF + 2 * bytesHB + bytesZB + bytesNB + bytesX1 + 1024;
  const size_t needA = needB + bytesXB;

  if (ws_size >= needB) {
    const bool haveXB = (ws_size >= needA);
    char* p = (char*)d_ws;
    bf16_t* wb = (bf16_t*)p;            p += bytesW;
    float* h0  = (float*)p;             p += bytesHF;
    float* h1  = (float*)p;             p += bytesHF;
    bf16_t* hb0 = (bf16_t*)p;           p += bytesHB;
    bf16_t* hb1 = (bf16_t*)p;           p += bytesHB;
    bf16_t* zb  = (bf16_t*)p;           p += bytesZB;
    bf16_t* nb  = (bf16_t*)p;           p += bytesNB;
    bf16_t* x1  = (bf16_t*)p;           p += bytesX1;
    bf16_t* xb  = haveXB ? (bf16_t*)p : nullptr;

    auto cast = [&](const float* s, bf16_t* d, int rs, int rp, int K, int ldp) {
      int g = rp > 8192 ? 8192 : rp;
      wcast_pad<<<g, 256, 0, stream>>>(s, d, rs, rp, K, ldp);
    };
    cast(eWih,   wb + oEih, 3 * HD, 3 * HD, XK,    XKP);
    cast(eWhh,   wb + oEhh, 3 * HD, 3 * HD, HD,    HD);
    cast(dWih,   wb + oDih, 3 * HD, 3 * HD, INDIM, INDIM);
    cast(dWhh,   wb + oDhh, 3 * HD, 3 * HD, HD,    HD);
    cast(fcMuW,  wb + oMu,  LATM,   1024,   HD,    HD);
    cast(fcLvW,  wb + oLv,  LATM,   1024,   HD,    HD);
    cast(fcOutW, wb + oOut, HD,     HD,     LATD,  LATD);
    cast(fcDecW, wb + oDec, INDIM,  INDIM,  HD,    HD);
    if (haveXB) cast(x, xb, TT * BB, TT * BB, XK, XKP);

    hipMemsetAsync(h0, 0, bytesHF, stream);
    hipMemsetAsync(hb0, 0, bytesHB, stream);

    float*  hF[2] = {h0, h1};
    bf16_t* hB[2] = {hb0, hb1};

    // ---- encoder ----
    for (int t = 0; t < TT; ++t) {
      const int ci = t & 1, co = ci ^ 1;
      const bf16_t* xt;
      if (haveXB) {
        xt = xb + (size_t)t * BB * XKP;
      } else {
        wcast_pad<<<512, 256, 0, stream>>>(x + (size_t)t * BB * XK, x1, BB, BB, XK, XKP);
        xt = x1;
      }
      gru3<<<512, 256, 0, stream>>>(xt, XKP, XKP / 64,
                                    wb + oEih, XKP, hB[ci], wb + oEhh,
                                    hF[ci], eBih, eBhh, hF[co], hB[co]);
    }
    // h_enc = hF[0]/hB[0]
    gemm_nt3<<<dim3(16, 8), 256, 0, stream>>>(hB[0], HD, HD, wb + oMu, HD, fcMuB,
                                              muO, LATM, LATM, nullptr, 0);
    gemm_nt3<<<dim3(16, 8), 256, 0, stream>>>(hB[0], HD, HD, wb + oLv, HD, fcLvB,
                                              lvO, LATM, LATM, nullptr, 0);
    build_zb<<<(BB * LATD) / 256, 256, 0, stream>>>(muO, lvO, eps, genre, zb);
    gemm_nt3<<<dim3(32, 8), 256, 0, stream>>>(zb, LATD, LATD, wb + oOut, LATD, fcOutB,
                                              hF[0], HD, HD, hB[0], HD);
    // ---- decoder ----
    for (int t = 0; t < TT; ++t) {
      const int ci = t & 1, co = ci ^ 1;
      gru3<<<512, 256, 0, stream>>>(t ? nb : (const bf16_t*)nullptr, INDIM,
                                    t ? INDIM / 64 : 0,
                                    wb + oDih, INDIM, hB[ci], wb + oDhh,
                                    hF[ci], dBih, dBhh, hF[co], hB[co]);
      gemm_nt3<<<dim3(8, 8), 256, 0, stream>>>(hB[co], HD, HD, wb + oDec, HD, fcDecB,
                                               out + (size_t)t * BB * INDIM, INDIM, INDIM,
                                               nb, INDIM);
    }
  } else {
    // ---- fp32 fallback ----
    float* h0 = (float*)d_ws;
    float* h1 = h0 + (size_t)BB * HD;
    float* zb = h1 + (size_t)BB * HD;
    hipMemsetAsync(h0, 0, (size_t)BB * HD * sizeof(float), stream);
    float* hF[2] = {h0, h1};
    for (int t = 0; t < TT; ++t) {
      const int ci = t & 1, co = ci ^ 1;
      gru_stepF<<<256, 256, 0, stream>>>(x + (size_t)t * BB * XK, XK, XK, eWih,
                                         hF[ci], eWhh, eBih, eBhh, hF[co]);
    }
    gemm_ntF<<<dim3(16, 8), 256, 0, stream>>>(hF[0], HD, HD, fcMuW, fcMuB, muO, LATM, LATM);
    gemm_ntF<<<dim3(16, 8), 256, 0, stream>>>(hF[0], HD, HD, fcLvW, fcLvB, lvO, LATM, LATM);
    build_zf<<<(BB * LATD) / 256, 256, 0, stream>>>(muO, lvO, eps, genre, zb);
    gemm_ntF<<<dim3(32, 8), 256, 0, stream>>>(zb, LATD, LATD, fcOutW, fcOutB, hF[0], HD, HD);
    for (int t = 0; t < TT; ++t) {
      const int ci = t & 1, co = ci ^ 1;
      gru_stepF<<<256, 256, 0, stream>>>(t ? out + (size_t)(t - 1) * BB * INDIM : nullptr,
                                         INDIM, INDIM, dWih, hF[ci], dWhh, dBih, dBhh, hF[co]);
      gemm_ntF<<<dim3(8, 8), 256, 0, stream>>>(hF[co], HD, HD, fcDecW, fcDecB,
                                               out + (size_t)t * BB * INDIM, INDIM, INDIM);
    }
  }
  (void)in_sizes; (void)n_in; (void)out_size;
}

// Round 8
// 21255.127 us; speedup vs baseline: 1.5984x; 1.0074x over previous
//
#include <hip/hip_runtime.h>
#include <hip/hip_bf16.h>

typedef __bf16 bf16_t;
typedef bf16_t bfx8 __attribute__((ext_vector_type(8)));
typedef float  fx4  __attribute__((ext_vector_type(4)));

#define TT     256
#define BB     512
#define INDIM  512
#define NGENRE 5
#define HD     2048
#define LATD   1024
#define LATM   1019
#define XK     517
#define XKP    576

// ---------------- helpers ----------------
__device__ __forceinline__ bf16_t f2b(float f) {
  unsigned u = __builtin_bit_cast(unsigned, f);
  u += 0x7fffu + ((u >> 16) & 1u);
  unsigned short s = (unsigned short)(u >> 16);
  return __builtin_bit_cast(bf16_t, s);
}
__device__ __forceinline__ float sigmoidf_(float x) { return 1.0f / (1.0f + __expf(-x)); }

__device__ __forceinline__ void gload16(const bf16_t* g, bf16_t* l) {
  __builtin_amdgcn_global_load_lds((const __attribute__((address_space(1))) void*)g,
                                   (__attribute__((address_space(3))) void*)l,
                                   16, 0, 0);
}
__device__ __forceinline__ void wait_vm0()  { asm volatile("s_waitcnt vmcnt(0)" ::: "memory"); }
__device__ __forceinline__ void wait_vm4()  { asm volatile("s_waitcnt vmcnt(4)" ::: "memory"); }
__device__ __forceinline__ void wait_vm5()  { asm volatile("s_waitcnt vmcnt(5)" ::: "memory"); }
__device__ __forceinline__ void wait_vm6()  { asm volatile("s_waitcnt vmcnt(6)" ::: "memory"); }
__device__ __forceinline__ void wait_vm10() { asm volatile("s_waitcnt vmcnt(10)" ::: "memory"); }
__device__ __forceinline__ void wait_vm12() { asm volatile("s_waitcnt vmcnt(12)" ::: "memory"); }
__device__ __forceinline__ void wait_lgkm0() { asm volatile("s_waitcnt lgkmcnt(0)" ::: "memory"); }

// ---------------- fp32 -> bf16 cast with row/col zero-padding ----------------
__global__ void wcast_pad(const float* __restrict__ src, bf16_t* __restrict__ dst,
                          int rows_src, int rows_pad, int K, int ldp) {
  for (int r = blockIdx.x; r < rows_pad; r += gridDim.x)
    for (int c = threadIdx.x; c < ldp; c += 256)
      dst[(size_t)r * ldp + c] = (r < rows_src && c < K) ? f2b(src[(size_t)r * K + c]) : f2b(0.0f);
}

// ---------------- fused GRU step v6: (m,j)=(128,16) traffic-optimal tile ----
// Block: 128 rows x 16 j-cols (x3 gates = 48 gate rows), 256 thr (4 waves).
// Waves split m (4 x 32 rows), share j. Per wave/iter: 12 MFMA : 10 ds_read.
// Staged bytes/step 294MB vs 415MB at (64,32). Grid 512 = 128 j-blk x 4 m-blk
// (2 blocks/CU). Depth-3; producer split: waves 0-1 = 4A+2B, waves 2-3 = 4A+1B.
// acc slots: 0=r 1=z 2=inn(phase0) 3=hn(phase1)
__global__ __launch_bounds__(256, 2)
void gru6(const bf16_t* __restrict__ A1, int lda1, int k1s,
          const bf16_t* __restrict__ Wih, int ldwih,
          const bf16_t* __restrict__ Hb,
          const bf16_t* __restrict__ Whh,
          const float* __restrict__ Hin,
          const float* __restrict__ bih, const float* __restrict__ bhh,
          float* __restrict__ Hout, bf16_t* __restrict__ HoutB)
{
  __shared__ bf16_t aT[3][128 * 64];
  __shared__ bf16_t bT[3][48 * 64];
  const int tid = threadIdx.x, wv = tid >> 6, lane = tid & 63;
  // XCD remap: xcd owns 16 consecutive j-blocks x 4 m-blocks.
  const int bid = blockIdx.x;
  const int xcd = bid & 7, loc = bid >> 3;       // loc 0..63
  const int j0 = (xcd * 16 + (loc >> 2)) * 16;   // 0..2032
  const int m0 = (loc & 3) * 128;                // 0..384
  const int lr = lane & 15, lk = lane >> 4;
  const int rl = lane >> 3;            // 0..7
  const int cl = (lane & 7) * 8;

  fx4 acc[2][4];   // [mfrag][slot]
#pragma unroll
  for (int m = 0; m < 2; ++m)
#pragma unroll
    for (int g = 0; g < 4; ++g) acc[m][g] = fx4{0.f, 0.f, 0.f, 0.f};

  const bf16_t* A1b = A1 ? A1 : Hb;

  // ---- staging offsets: A 16 groups (4/wave); B 6 groups (wv0:2 wv1:2 wv2:1 wv3:1)
  int aOff0[4], aOff1[4], aSlot[4];
#pragma unroll
  for (int i = 0; i < 4; ++i) {
    const int t = wv * 4 + i;            // 0..15
    const int r = t * 8 + rl;            // 0..127
    const int c = cl ^ ((r & 7) * 8);
    aOff0[i] = (m0 + r) * lda1 + c;
    aOff1[i] = (m0 + r) * HD + c;
    aSlot[i] = t * 512;
  }
  const int nB  = (wv < 2) ? 2 : 1;
  const int bt0 = (wv < 2) ? wv * 2 : (2 + wv); // wv2->4, wv3->5
  int bOff0[2], bOff1[2], bSlot[2];
#pragma unroll
  for (int i = 0; i < 2; ++i) {
    const int t = bt0 + (i < nB ? i : 0);
    const int r = t * 8 + rl;            // 0..47
    const int g = r >> 4, jj = r & 15;
    const int c = cl ^ ((r & 7) * 8);
    bOff0[i] = (g * HD + j0 + jj) * ldwih + c;
    bOff1[i] = (g * HD + j0 + jj) * HD + c;
    bSlot[i] = t * 512;
  }

  // ---- fragment read offsets (swizzled) ----
  int aRow[2], bRow[3], ko[2];
#pragma unroll
  for (int m = 0; m < 2; ++m) aRow[m] = (wv * 32 + m * 16 + lr) * 64;
#pragma unroll
  for (int g = 0; g < 3; ++g) bRow[g] = (g * 16 + lr) * 64;
#pragma unroll
  for (int h = 0; h < 2; ++h) ko[h] = (h * 32 + lk * 8) ^ ((lr & 7) * 8);

  auto stage = [&](int buf, int s) {
    const bool p = (s >= k1s);
    const int kb = (p ? (s - k1s) : s) * 64;
    bf16_t* aD = &aT[buf][0];
    bf16_t* bD = &bT[buf][0];
    if (p) {
#pragma unroll
      for (int i = 0; i < 4; ++i) gload16(Hb + aOff1[i] + kb, aD + aSlot[i]);
      gload16(Whh + bOff1[0] + kb, bD + bSlot[0]);
      if (wv < 2) gload16(Whh + bOff1[1] + kb, bD + bSlot[1]);
    } else {
#pragma unroll
      for (int i = 0; i < 4; ++i) gload16(A1b + aOff0[i] + kb, aD + aSlot[i]);
      gload16(Wih + bOff0[0] + kb, bD + bSlot[0]);
      if (wv < 2) gload16(Wih + bOff0[1] + kb, bD + bSlot[1]);
    }
  };

  const int nk = k1s + HD / 64;          // >= 32
  stage(0, 0); stage(1, 1); stage(2, 2);
  int buf = 0;
  for (int s = 0; s < nk; ++s) {
    const int rem = nk - 1 - s;
    if (rem >= 2)      { if (wv < 2) wait_vm12(); else wait_vm10(); }
    else if (rem == 1) { if (wv < 2) wait_vm6();  else wait_vm5();  }
    else               wait_vm0();
    __builtin_amdgcn_s_barrier();        // tile s resident
    const bf16_t* aB = &aT[buf][0];
    const bf16_t* bB = &bT[buf][0];
    bfx8 af[2][2], bfr[3][2];
#pragma unroll
    for (int m = 0; m < 2; ++m)
#pragma unroll
      for (int h = 0; h < 2; ++h)
        af[m][h] = *reinterpret_cast<const bfx8*>(&aB[aRow[m] + ko[h]]);
#pragma unroll
    for (int g = 0; g < 3; ++g)
#pragma unroll
      for (int h = 0; h < 2; ++h)
        bfr[g][h] = *reinterpret_cast<const bfx8*>(&bB[bRow[g] + ko[h]]);
    wait_lgkm0();
    __builtin_amdgcn_sched_barrier(0);
    __builtin_amdgcn_s_barrier();        // all waves done reading buf
    if (s + 3 < nk) stage(buf, s + 3);
    const bool p = (s >= k1s);
    __builtin_amdgcn_s_setprio(1);
#pragma unroll
    for (int h = 0; h < 2; ++h)
#pragma unroll
      for (int g = 0; g < 3; ++g) {
        const int slot = (g == 2) ? (p ? 3 : 2) : g;
#pragma unroll
        for (int m = 0; m < 2; ++m)
          acc[m][slot] = __builtin_amdgcn_mfma_f32_16x16x32_bf16(af[m][h], bfr[g][h], acc[m][slot], 0, 0, 0);
      }
    __builtin_amdgcn_s_setprio(0);
    buf = (buf == 2) ? 0 : buf + 1;
  }

  // ---- epilogue: gates + h update (wave: 32 rows x 16 cols) ----
  const int col = j0 + lr;
  const float br  = bih[col] + bhh[col];
  const float bz  = bih[HD + col] + bhh[HD + col];
  const float bin = bih[2 * HD + col];
  const float bhn = bhh[2 * HD + col];
#pragma unroll
  for (int m = 0; m < 2; ++m) {
    const int rbase = m0 + wv * 32 + m * 16 + lk * 4;
#pragma unroll
    for (int q = 0; q < 4; ++q) {
      const int row = rbase + q;
      const float r = sigmoidf_(acc[m][0][q] + br);
      const float z = sigmoidf_(acc[m][1][q] + bz);
      const float n = tanhf(acc[m][2][q] + bin + r * (acc[m][3][q] + bhn));
      const float hv = (1.0f - z) * n + z * Hin[(size_t)row * HD + col];
      Hout[(size_t)row * HD + col]  = hv;
      HoutB[(size_t)row * HD + col] = f2b(hv);
    }
  }
}

// ---------------- bf16 NT GEMM (counted-vmcnt pipeline, depth-2) ----------------
__global__ __launch_bounds__(256, 2)
void gemm_nt3(const bf16_t* __restrict__ A, int lda, int K,
              const bf16_t* __restrict__ W, int ldw,
              const float* __restrict__ bias,
              float* __restrict__ O, int ldo, int N,
              bf16_t* __restrict__ OB, int ldob)
{
  __shared__ bf16_t aT[2][64 * 64];
  __shared__ bf16_t bT[2][64 * 64];
  const int tid = threadIdx.x, wave = tid >> 6, lane = tid & 63;
  const int m0 = blockIdx.y * 64, n0 = blockIdx.x * 64;
  const int wm = wave & 1, wn = wave >> 1;
  const int lr = lane & 15, lk = lane >> 4;
  const int rl = lane >> 3, cl = (lane & 7) * 8;

  fx4 acc[2][2];
#pragma unroll
  for (int a = 0; a < 2; ++a)
#pragma unroll
    for (int b = 0; b < 2; ++b) acc[a][b] = fx4{0.f, 0.f, 0.f, 0.f};

  const bf16_t* pA[2]; const bf16_t* pB[2]; int slot[2];
#pragma unroll
  for (int i = 0; i < 2; ++i) {
    const int t = wave * 2 + i;
    const int r = t * 8 + rl;
    const int c = cl ^ ((r & 7) * 8);
    pA[i] = A + (size_t)(m0 + r) * lda + c;
    pB[i] = W + (size_t)(n0 + r) * ldw + c;
    slot[i] = t * 512;
  }
  int aRow[2], bRow[2], ko[2];
#pragma unroll
  for (int f = 0; f < 2; ++f) {
    aRow[f] = (wm * 32 + f * 16 + lr) * 64;
    bRow[f] = (wn * 32 + f * 16 + lr) * 64;
  }
#pragma unroll
  for (int h = 0; h < 2; ++h) ko[h] = (h * 32 + lk * 8) ^ ((lr & 7) * 8);

  auto stage = [&](int buf, int kb) {
#pragma unroll
    for (int i = 0; i < 2; ++i) {
      gload16(pA[i] + kb, &aT[buf][slot[i]]);
      gload16(pB[i] + kb, &bT[buf][slot[i]]);
    }
  };

  const int nk = K >> 6;
  stage(0, 0);
  stage(1, 64);
  for (int s = 0; s < nk; ++s) {
    if (s == nk - 1) wait_vm0(); else wait_vm4();
    __builtin_amdgcn_s_barrier();
    const bf16_t* aB = &aT[s & 1][0];
    const bf16_t* bB = &bT[s & 1][0];
    bfx8 af[2][2], bfr[2][2];
#pragma unroll
    for (int f = 0; f < 2; ++f)
#pragma unroll
      for (int h = 0; h < 2; ++h) {
        af[f][h]  = *reinterpret_cast<const bfx8*>(&aB[aRow[f] + ko[h]]);
        bfr[f][h] = *reinterpret_cast<const bfx8*>(&bB[bRow[f] + ko[h]]);
      }
    wait_lgkm0();
    __builtin_amdgcn_sched_barrier(0);
    __builtin_amdgcn_s_barrier();
    if (s + 2 < nk) stage(s & 1, (s + 2) << 6);
    __builtin_amdgcn_s_setprio(1);
#pragma unroll
    for (int h = 0; h < 2; ++h)
#pragma unroll
      for (int fm = 0; fm < 2; ++fm)
#pragma unroll
        for (int fj = 0; fj < 2; ++fj)
          acc[fm][fj] = __builtin_amdgcn_mfma_f32_16x16x32_bf16(af[fm][h], bfr[fj][h], acc[fm][fj], 0, 0, 0);
    __builtin_amdgcn_s_setprio(0);
  }

#pragma unroll
  for (int fm = 0; fm < 2; ++fm)
#pragma unroll
    for (int fj = 0; fj < 2; ++fj) {
      const int col = n0 + wn * 32 + fj * 16 + lr;
      if (col < N) {
        const float bb = bias[col];
#pragma unroll
        for (int q = 0; q < 4; ++q) {
          const int row = m0 + wm * 32 + fm * 16 + lk * 4 + q;
          const float v = acc[fm][fj][q] + bb;
          O[(size_t)row * ldo + col] = v;
          if (OB) OB[(size_t)row * ldob + col] = f2b(v);
        }
      }
    }
}

// ---------------- z build (writes bf16) ----------------
__global__ void build_zb(const float* __restrict__ mu, const float* __restrict__ lv,
                         const float* __restrict__ eps, const float* __restrict__ genre,
                         bf16_t* __restrict__ zb) {
  int i = blockIdx.x * 256 + threadIdx.x;
  int b = i >> 10, c = i & 1023;
  float v;
  if (c < LATM) {
    size_t k = (size_t)b * LATM + c;
    v = mu[k] + expf(0.5f * lv[k]) * eps[k];
  } else {
    v = genre[b * NGENRE + (c - LATM)];
  }
  zb[i] = f2b(v);
}

// ================= fp32 fallback =================
__global__ __launch_bounds__(256, 1)
void gru_stepF(const float* __restrict__ A1, int lda1, int K1,
               const float* __restrict__ Wih,
               const float* __restrict__ Hin,
               const float* __restrict__ Whh,
               const float* __restrict__ bih, const float* __restrict__ bhh,
               float* __restrict__ Hout)
{
  __shared__ bf16_t a_lds[128][32];
  __shared__ bf16_t b_lds[96][32];
  const int tid = threadIdx.x, wave = tid >> 6, lane = tid & 63;
  const int m0 = (blockIdx.x >> 6) * 128, j0 = (blockIdx.x & 63) * 32;
  const int lr = lane & 15, lk = lane >> 4;
  fx4 acc[2][2][4];
#pragma unroll
  for (int a = 0; a < 2; ++a)
#pragma unroll
    for (int b = 0; b < 2; ++b)
#pragma unroll
      for (int g = 0; g < 4; ++g) acc[a][b][g] = fx4{0.f, 0.f, 0.f, 0.f};

  for (int ph = 0; ph < 2; ++ph) {
    const float* Ag = ph ? Hin : A1;
    const int lda = ph ? HD : lda1, kLen = ph ? HD : K1;
    const float* W = ph ? Whh : Wih;
    const int nslot = ph ? 3 : 2;
    const int nkk = (kLen + 31) >> 5;
    for (int s = 0; s < nkk; ++s) {
      const int kb = s << 5;
#pragma unroll
      for (int it = 0; it < 16; ++it) {
        int i = tid + it * 256;
        int r = i >> 5, kk = i & 31, gk = kb + kk;
        float v = 0.0f;
        if (Ag && gk < kLen) v = Ag[(size_t)(m0 + r) * lda + gk];
        a_lds[r][kk] = f2b(v);
      }
#pragma unroll
      for (int it = 0; it < 12; ++it) {
        int i = tid + it * 256;
        int r = i >> 5, kk = i & 31, g = r >> 5, jj = r & 31, gk = kb + kk;
        b_lds[r][kk] = (gk < kLen) ? f2b(W[(size_t)(g * HD + j0 + jj) * kLen + gk]) : f2b(0.0f);
      }
      __syncthreads();
      bfx8 af[2];
#pragma unroll
      for (int fm = 0; fm < 2; ++fm)
        af[fm] = *reinterpret_cast<const bfx8*>(&a_lds[wave * 32 + fm * 16 + lr][lk * 8]);
#pragma unroll
      for (int g = 0; g < 3; ++g) {
        const int slot = (g == 2) ? nslot : g;
#pragma unroll
        for (int fj = 0; fj < 2; ++fj) {
          bfx8 bfr = *reinterpret_cast<const bfx8*>(&b_lds[g * 32 + fj * 16 + lr][lk * 8]);
#pragma unroll
          for (int fm = 0; fm < 2; ++fm)
            acc[fm][fj][slot] = __builtin_amdgcn_mfma_f32_16x16x32_bf16(af[fm], bfr, acc[fm][fj][slot], 0, 0, 0);
        }
      }
      __syncthreads();
    }
  }
#pragma unroll
  for (int fj = 0; fj < 2; ++fj) {
    const int col = j0 + fj * 16 + lr;
    const float br = bih[col] + bhh[col];
    const float bz = bih[HD + col] + bhh[HD + col];
    const float bin = bih[2 * HD + col];
    const float bhn = bhh[2 * HD + col];
#pragma unroll
    for (int fm = 0; fm < 2; ++fm) {
      const int rbase = m0 + wave * 32 + fm * 16 + lk * 4;
#pragma unroll
      for (int q = 0; q < 4; ++q) {
        const int row = rbase + q;
        const float r = sigmoidf_(acc[fm][fj][0][q] + br);
        const float z = sigmoidf_(acc[fm][fj][1][q] + bz);
        const float n = tanhf(acc[fm][fj][2][q] + bin + r * (acc[fm][fj][3][q] + bhn));
        Hout[(size_t)row * HD + col] = (1.0f - z) * n + z * Hin[(size_t)row * HD + col];
      }
    }
  }
}

__global__ __launch_bounds__(256, 1)
void gemm_ntF(const float* __restrict__ A, int lda, int K,
              const float* __restrict__ W,
              const float* __restrict__ bias,
              float* __restrict__ O, int ldo, int N)
{
  __shared__ bf16_t a_lds[64][32];
  __shared__ bf16_t b_lds[64][32];
  const int tid = threadIdx.x, wave = tid >> 6, lane = tid & 63;
  const int m0 = blockIdx.y * 64, n0 = blockIdx.x * 64;
  const int wm = (wave & 1) * 32, wn = (wave >> 1) * 32;
  const int lr = lane & 15, lk = lane >> 4;
  fx4 acc[2][2];
#pragma unroll
  for (int a = 0; a < 2; ++a)
#pragma unroll
    for (int b = 0; b < 2; ++b) acc[a][b] = fx4{0.f, 0.f, 0.f, 0.f};
  for (int kb = 0; kb < K; kb += 32) {
#pragma unroll
    for (int it = 0; it < 8; ++it) {
      int i = tid + it * 256;
      int r = i >> 5, kk = i & 31;
      a_lds[r][kk] = f2b(A[(size_t)(m0 + r) * lda + kb + kk]);
    }
#pragma unroll
    for (int it = 0; it < 8; ++it) {
      int i = tid + it * 256;
      int r = i >> 5, kk = i & 31;
      int n = n0 + r;
      b_lds[r][kk] = (n < N) ? f2b(W[(size_t)n * K + kb + kk]) : f2b(0.0f);
    }
    __syncthreads();
    bfx8 af[2], bfr[2];
#pragma unroll
    for (int f = 0; f < 2; ++f) {
      af[f] = *reinterpret_cast<const bfx8*>(&a_lds[wm + f * 16 + lr][lk * 8]);
      bfr[f] = *reinterpret_cast<const bfx8*>(&b_lds[wn + f * 16 + lr][lk * 8]);
    }
#pragma unroll
    for (int fm = 0; fm < 2; ++fm)
#pragma unroll
      for (int fj = 0; fj < 2; ++fj)
        acc[fm][fj] = __builtin_amdgcn_mfma_f32_16x16x32_bf16(af[fm], bfr[fj], acc[fm][fj], 0, 0, 0);
    __syncthreads();
  }
#pragma unroll
  for (int fm = 0; fm < 2; ++fm)
#pragma unroll
    for (int fj = 0; fj < 2; ++fj) {
      const int col = n0 + wn + fj * 16 + lr;
      if (col < N) {
        const float bb = bias[col];
#pragma unroll
        for (int q = 0; q < 4; ++q) {
          const int row = m0 + wm + fm * 16 + lk * 4 + q;
          O[(size_t)row * ldo + col] = acc[fm][fj][q] + bb;
        }
      }
    }
}

__global__ void build_zf(const float* __restrict__ mu, const float* __restrict__ lv,
                         const float* __restrict__ eps, const float* __restrict__ genre,
                         float* __restrict__ z) {
  int i = blockIdx.x * 256 + threadIdx.x;
  int b = i >> 10, c = i & 1023;
  z[i] = (c < LATM) ? mu[(size_t)b * LATM + c] + expf(0.5f * lv[(size_t)b * LATM + c]) * eps[(size_t)b * LATM + c]
                    : genre[b * NGENRE + (c - LATM)];
}

// ---------------- host ----------------
extern "C" void kernel_launch(void* const* d_in, const int* in_sizes, int n_in,
                              void* d_out, int out_size, void* d_ws, size_t ws_size,
                              hipStream_t stream) {
  const float* x      = (const float*)d_in[0];
  const float* genre  = (const float*)d_in[1];
  const float* eps    = (const float*)d_in[2];
  const float* eWih   = (const float*)d_in[3];
  const float* eWhh   = (const float*)d_in[4];
  const float* eBih   = (const float*)d_in[5];
  const float* eBhh   = (const float*)d_in[6];
  const float* dWih   = (const float*)d_in[7];
  const float* dWhh   = (const float*)d_in[8];
  const float* dBih   = (const float*)d_in[9];
  const float* dBhh   = (const float*)d_in[10];
  const float* fcMuW  = (const float*)d_in[11];
  const float* fcMuB  = (const float*)d_in[12];
  const float* fcLvW  = (const float*)d_in[13];
  const float* fcLvB  = (const float*)d_in[14];
  const float* fcOutW = (const float*)d_in[15];
  const float* fcOutB = (const float*)d_in[16];
  const float* fcDecW = (const float*)d_in[17];
  const float* fcDecB = (const float*)d_in[18];

  float* out = (float*)d_out;
  float* muO = out + (size_t)TT * BB * INDIM;
  float* lvO = muO + (size_t)BB * LATM;

  const size_t nEih = (size_t)3 * HD * XKP;
  const size_t nEhh = (size_t)3 * HD * HD;
  const size_t nDih = (size_t)3 * HD * INDIM;
  const size_t nDhh = (size_t)3 * HD * HD;
  const size_t nMu  = (size_t)1024 * HD;
  const size_t nOut = (size_t)HD * LATD;
  const size_t nDec = (size_t)INDIM * HD;
  const size_t oEih = 0;
  const size_t oEhh = oEih + nEih;
  const size_t oDih = oEhh + nEhh;
  const size_t oDhh = oDih + nDih;
  const size_t oMu  = oDhh + nDhh;
  const size_t oLv  = oMu + nMu;
  const size_t oOut = oLv + nMu;
  const size_t oDec = oOut + nOut;
  const size_t wTot = oDec + nDec;

  const size_t bytesW  = wTot * 2;
  const size_t bytesHF = (size_t)BB * HD * 4;
  const size_t bytesHB = (size_t)BB * HD * 2;
  const size_t bytesZB = (size_t)BB * LATD * 2;
  const size_t bytesNB = (size_t)BB * INDIM * 2;
  const size_t bytesX1 = (size_t)BB * XKP * 2;
  const size_t bytesXB = (size_t)TT * BB * XKP * 2;
  const size_t needB = bytesW + 2 * bytesHF + 2 * bytesHB + bytesZB + bytesNB + bytesX1 + 1024;
  const size_t needA = needB + bytesXB;

  if (ws_size >= needB) {
    const bool haveXB = (ws_size >= needA);
    char* p = (char*)d_ws;
    bf16_t* wb = (bf16_t*)p;            p += bytesW;
    float* h0  = (float*)p;             p += bytesHF;
    float* h1  = (float*)p;             p += bytesHF;
    bf16_t* hb0 = (bf16_t*)p;           p += bytesHB;
    bf16_t* hb1 = (bf16_t*)p;           p += bytesHB;
    bf16_t* zb  = (bf16_t*)p;           p += bytesZB;
    bf16_t* nb  = (bf16_t*)p;           p += bytesNB;
    bf16_t* x1  = (bf16_t*)p;           p += bytesX1;
    bf16_t* xb  = haveXB ? (bf16_t*)p : nullptr;

    auto cast = [&](const float* s, bf16_t* d, int rs, int rp, int K, int ldp) {
      int g = rp > 8192 ? 8192 : rp;
      wcast_pad<<<g, 256, 0, stream>>>(s, d, rs, rp, K, ldp);
    };
    cast(eWih,   wb + oEih, 3 * HD, 3 * HD, XK,    XKP);
    cast(eWhh,   wb + oEhh, 3 * HD, 3 * HD, HD,    HD);
    cast(dWih,   wb + oDih, 3 * HD, 3 * HD, INDIM, INDIM);
    cast(dWhh,   wb + oDhh, 3 * HD, 3 * HD, HD,    HD);
    cast(fcMuW,  wb + oMu,  LATM,   1024,   HD,    HD);
    cast(fcLvW,  wb + oLv,  LATM,   1024,   HD,    HD);
    cast(fcOutW, wb + oOut, HD,     HD,     LATD,  LATD);
    cast(fcDecW, wb + oDec, INDIM,  INDIM,  HD,    HD);
    if (haveXB) cast(x, xb, TT * BB, TT * BB, XK, XKP);

    hipMemsetAsync(h0, 0, bytesHF, stream);
    hipMemsetAsync(hb0, 0, bytesHB, stream);

    float*  hF[2] = {h0, h1};
    bf16_t* hB[2] = {hb0, hb1};

    // ---- encoder ----
    for (int t = 0; t < TT; ++t) {
      const int ci = t & 1, co = ci ^ 1;
      const bf16_t* xt;
      if (haveXB) {
        xt = xb + (size_t)t * BB * XKP;
      } else {
        wcast_pad<<<512, 256, 0, stream>>>(x + (size_t)t * BB * XK, x1, BB, BB, XK, XKP);
        xt = x1;
      }
      gru6<<<512, 256, 0, stream>>>(xt, XKP, XKP / 64,
                                    wb + oEih, XKP, hB[ci], wb + oEhh,
                                    hF[ci], eBih, eBhh, hF[co], hB[co]);
    }
    // h_enc = hF[0]/hB[0]
    gemm_nt3<<<dim3(16, 8), 256, 0, stream>>>(hB[0], HD, HD, wb + oMu, HD, fcMuB,
                                              muO, LATM, LATM, nullptr, 0);
    gemm_nt3<<<dim3(16, 8), 256, 0, stream>>>(hB[0], HD, HD, wb + oLv, HD, fcLvB,
                                              lvO, LATM, LATM, nullptr, 0);
    build_zb<<<(BB * LATD) / 256, 256, 0, stream>>>(muO, lvO, eps, genre, zb);
    gemm_nt3<<<dim3(32, 8), 256, 0, stream>>>(zb, LATD, LATD, wb + oOut, LATD, fcOutB,
                                              hF[0], HD, HD, hB[0], HD);
    // ---- decoder ----
    for (int t = 0; t < TT; ++t) {
      const int ci = t & 1, co = ci ^ 1;
      gru6<<<512, 256, 0, stream>>>(t ? nb : (const bf16_t*)nullptr, INDIM,
                                    t ? INDIM / 64 : 0,
                                    wb + oDih, INDIM, hB[ci], wb + oDhh,
                                    hF[ci], dBih, dBhh, hF[co], hB[co]);
      gemm_nt3<<<dim3(8, 8), 256, 0, stream>>>(hB[co], HD, HD, wb + oDec, HD, fcDecB,
                                               out + (size_t)t * BB * INDIM, INDIM, INDIM,
                                               nb, INDIM);
    }
  } else {
    // ---- fp32 fallback ----
    float* h0 = (float*)d_ws;
    float* h1 = h0 + (size_t)BB * HD;
    float* zb = h1 + (size_t)BB * HD;
    hipMemsetAsync(h0, 0, (size_t)BB * HD * sizeof(float), stream);
    float* hF[2] = {h0, h1};
    for (int t = 0; t < TT; ++t) {
      const int ci = t & 1, co = ci ^ 1;
      gru_stepF<<<256, 256, 0, stream>>>(x + (size_t)t * BB * XK, XK, XK, eWih,
                                         hF[ci], eWhh, eBih, eBhh, hF[co]);
    }
    gemm_ntF<<<dim3(16, 8), 256, 0, stream>>>(hF[0], HD, HD, fcMuW, fcMuB, muO, LATM, LATM);
    gemm_ntF<<<dim3(16, 8), 256, 0, stream>>>(hF[0], HD, HD, fcLvW, fcLvB, lvO, LATM, LATM);
    build_zf<<<(BB * LATD) / 256, 256, 0, stream>>>(muO, lvO, eps, genre, zb);
    gemm_ntF<<<dim3(32, 8), 256, 0, stream>>>(zb, LATD, LATD, fcOutW, fcOutB, hF[0], HD, HD);
    for (int t = 0; t < TT; ++t) {
      const int ci = t & 1, co = ci ^ 1;
      gru_stepF<<<256, 256, 0, stream>>>(t ? out + (size_t)(t - 1) * BB * INDIM : nullptr,
                                         INDIM, INDIM, dWih, hF[ci], dWhh, dBih, dBhh, hF[co]);
      gemm_ntF<<<dim3(8, 8), 256, 0, stream>>>(hF[co], HD, HD, fcDecW, fcDecB,
                                               out + (size_t)t * BB * INDIM, INDIM, INDIM);
    }
  }
  (void)in_sizes; (void)n_in; (void)out_size;
}

// Round 9
// 17117.566 us; speedup vs baseline: 1.9848x; 1.2417x over previous
//
#include <hip/hip_runtime.h>
#include <hip/hip_bf16.h>

typedef __bf16 bf16_t;
typedef bf16_t bfx8 __attribute__((ext_vector_type(8)));
typedef float  fx4  __attribute__((ext_vector_type(4)));

#define TT     256
#define BB     512
#define INDIM  512
#define NGENRE 5
#define HD     2048
#define LATD   1024
#define LATM   1019
#define XK     517
#define XKP    576
#define CHUNK  64

// ---------------- helpers ----------------
__device__ __forceinline__ bf16_t f2b(float f) {
  unsigned u = __builtin_bit_cast(unsigned, f);
  u += 0x7fffu + ((u >> 16) & 1u);
  unsigned short s = (unsigned short)(u >> 16);
  return __builtin_bit_cast(bf16_t, s);
}
__device__ __forceinline__ float sigmoidf_(float x) { return 1.0f / (1.0f + __expf(-x)); }

__device__ __forceinline__ void gload16(const bf16_t* g, bf16_t* l) {
  __builtin_amdgcn_global_load_lds((const __attribute__((address_space(1))) void*)g,
                                   (__attribute__((address_space(3))) void*)l,
                                   16, 0, 0);
}
__device__ __forceinline__ void wait_vm0()  { asm volatile("s_waitcnt vmcnt(0)" ::: "memory"); }
__device__ __forceinline__ void wait_vm4()  { asm volatile("s_waitcnt vmcnt(4)" ::: "memory"); }
__device__ __forceinline__ void wait_vm5()  { asm volatile("s_waitcnt vmcnt(5)" ::: "memory"); }
__device__ __forceinline__ void wait_vm6()  { asm volatile("s_waitcnt vmcnt(6)" ::: "memory"); }
__device__ __forceinline__ void wait_vm10() { asm volatile("s_waitcnt vmcnt(10)" ::: "memory"); }
__device__ __forceinline__ void wait_vm12() { asm volatile("s_waitcnt vmcnt(12)" ::: "memory"); }
__device__ __forceinline__ void wait_lgkm0() { asm volatile("s_waitcnt lgkmcnt(0)" ::: "memory"); }

// ---------------- fp32 -> bf16 cast with row/col zero-padding ----------------
__global__ void wcast_pad(const float* __restrict__ src, bf16_t* __restrict__ dst,
                          int rows_src, int rows_pad, int K, int ldp) {
  for (int r = blockIdx.x; r < rows_pad; r += gridDim.x)
    for (int c = threadIdx.x; c < ldp; c += 256)
      dst[(size_t)r * ldp + c] = (r < rows_src && c < K) ? f2b(src[(size_t)r * K + c]) : f2b(0.0f);
}

// ---------------- small prep kernels (decoder composition) ----------------
// fcDecW (512 x 2048) fp32 -> WdecT (2048 x 512) bf16
__global__ void wtransp(const float* __restrict__ src, bf16_t* __restrict__ dst) {
  int i = blockIdx.x * 256 + threadIdx.x;     // over 2048*512
  int r = i >> 9, c = i & 511;
  dst[i] = f2b(src[(size_t)c * 2048 + r]);
}
// bc = dWih (6144 x 512) @ fcDecB (512)
__global__ void bcomp(const float* __restrict__ wih, const float* __restrict__ bdec,
                      float* __restrict__ bc) {
  int r = blockIdx.x * 256 + threadIdx.x;
  if (r >= 3 * HD) return;
  float s = 0.f;
  for (int k = 0; k < 512; ++k) s += wih[(size_t)r * 512 + k] * bdec[k];
  bc[r] = s;
}
// bias4 vectors: {cR, cZ, cI, cH} per column, for t>=1 (bD) and t==0 (bD0)
__global__ void biasbuild(const float* __restrict__ bc, const float* __restrict__ bih,
                          const float* __restrict__ bhh,
                          float4* __restrict__ bD, float4* __restrict__ bD0) {
  int c = blockIdx.x * 256 + threadIdx.x;
  if (c >= HD) return;
  float r0 = bih[c] + bhh[c];
  float z0 = bih[HD + c] + bhh[HD + c];
  float i0 = bih[2 * HD + c];
  float h0 = bhh[2 * HD + c];
  bD0[c] = float4{r0, z0, i0, h0};
  bD[c]  = float4{r0 + bc[c], z0 + bc[HD + c], i0 + bc[2 * HD + c], h0};
}
// W' (8192x2048): g0=Wc_r+Whh_r g1=Wc_z+Whh_z g2=Wc_n g3=Whh_n ; W0': Whh_r,Whh_z,0,Whh_n
__global__ void wprime(const bf16_t* __restrict__ wc, const bf16_t* __restrict__ whh,
                       bf16_t* __restrict__ wp, bf16_t* __restrict__ wp0) {
  const size_t total = (size_t)4 * HD * HD;
  for (size_t i = (size_t)blockIdx.x * 256 + threadIdx.x; i < total; i += (size_t)gridDim.x * 256) {
    int row = (int)(i >> 11), k = (int)(i & 2047);
    int g = row >> 11, j = row & 2047;
    bf16_t v, v0;
    if (g == 0) {
      float a = (float)wc[(size_t)j * HD + k], b = (float)whh[(size_t)j * HD + k];
      v = f2b(a + b); v0 = whh[(size_t)j * HD + k];
    } else if (g == 1) {
      size_t o = (size_t)(HD + j) * HD + k;
      v = f2b((float)wc[o] + (float)whh[o]); v0 = whh[o];
    } else if (g == 2) {
      v = wc[(size_t)(2 * HD + j) * HD + k]; v0 = f2b(0.0f);
    } else {
      v = whh[(size_t)(2 * HD + j) * HD + k]; v0 = v;
    }
    wp[i] = v; wp0[i] = v0;
  }
}

// ---------------- composed decoder GRU step: single-phase K=2048, 4 gates ----
// Block 64 rows x 32 j (x4 gates), 256 thr (4 waves), grid 512 (2 blocks/CU).
// 1-barrier/iter pipeline, 3 LDS buffers, 6 gload16/wave/stage, waits vm6/vm0.
// acc slots: 0=r 1=z 2=inn 3=hn ; epilogue bias4 = {cR,cZ,cI,cH}.
__global__ __launch_bounds__(256, 2)
void gruC(const bf16_t* __restrict__ Hb,
          const bf16_t* __restrict__ Wp,          // 8192 x 2048
          const float4* __restrict__ bias4,
          const float* __restrict__ Hin,
          float* __restrict__ Hout, bf16_t* __restrict__ HoutB)
{
  __shared__ bf16_t aT[3][64 * 64];
  __shared__ bf16_t bT[3][128 * 64];
  const int tid = threadIdx.x, wv = tid >> 6, lane = tid & 63;
  const int bid = blockIdx.x;
  const int j0 = (bid & 63) * 32;
  const int m0 = (bid >> 6) * 64;
  const int lr = lane & 15, lk = lane >> 4;
  const int rl = lane >> 3;
  const int cl = (lane & 7) * 8;

  fx4 acc[2][4];
#pragma unroll
  for (int fj = 0; fj < 2; ++fj)
#pragma unroll
    for (int g = 0; g < 4; ++g) acc[fj][g] = fx4{0.f, 0.f, 0.f, 0.f};

  // staging offsets
  int aOff[2], aSlot[2];
#pragma unroll
  for (int i = 0; i < 2; ++i) {
    const int t = wv * 2 + i;              // 0..7
    const int r = t * 8 + rl;              // 0..63
    const int c = cl ^ ((r & 7) * 8);
    aOff[i] = (m0 + r) * HD + c;
    aSlot[i] = t * 512;
  }
  int bOff[4], bSlot[4];
#pragma unroll
  for (int i = 0; i < 4; ++i) {
    const int t = wv * 4 + i;              // 0..15
    const int r = t * 8 + rl;              // 0..127
    const int g = r >> 5, jj = r & 31;
    const int c = cl ^ ((r & 7) * 8);
    bOff[i] = (g * HD + j0 + jj) * HD + c;
    bSlot[i] = t * 512;
  }
  // fragment offsets
  int aRow, bRow[4][2], ko[2];
  aRow = (wv * 16 + lr) * 64;
#pragma unroll
  for (int g = 0; g < 4; ++g)
#pragma unroll
    for (int fj = 0; fj < 2; ++fj) bRow[g][fj] = (g * 32 + fj * 16 + lr) * 64;
#pragma unroll
  for (int h = 0; h < 2; ++h) ko[h] = (h * 32 + lk * 8) ^ ((lr & 7) * 8);

  auto stage = [&](int buf, int s) {
    const int kb = s * 64;
#pragma unroll
    for (int i = 0; i < 2; ++i) gload16(Hb + aOff[i] + kb, &aT[buf][aSlot[i]]);
#pragma unroll
    for (int i = 0; i < 4; ++i) gload16(Wp + bOff[i] + kb, &bT[buf][bSlot[i]]);
  };

  const int nk = HD / 64;                  // 32
  stage(0, 0); stage(1, 1);
  int rb = 0, sb = 2;
  for (int s = 0; s < nk; ++s) {
    if (s == nk - 1) wait_vm0(); else wait_vm6();
    __builtin_amdgcn_s_barrier();          // tile s resident; tile s-1 reads done (all waves)
    if (s + 2 < nk) stage(sb, s + 2);      // overwrite tile s-1's buffer
    const bf16_t* aB = &aT[rb][0];
    const bf16_t* bB = &bT[rb][0];
    bfx8 af[2]; bfx8 bfr[4][2][2];
#pragma unroll
    for (int h = 0; h < 2; ++h)
      af[h] = *reinterpret_cast<const bfx8*>(&aB[aRow + ko[h]]);
#pragma unroll
    for (int g = 0; g < 4; ++g)
#pragma unroll
      for (int fj = 0; fj < 2; ++fj)
#pragma unroll
        for (int h = 0; h < 2; ++h)
          bfr[g][fj][h] = *reinterpret_cast<const bfx8*>(&bB[bRow[g][fj] + ko[h]]);
    wait_lgkm0();
    __builtin_amdgcn_sched_barrier(0);
    __builtin_amdgcn_s_setprio(1);
#pragma unroll
    for (int h = 0; h < 2; ++h)
#pragma unroll
      for (int g = 0; g < 4; ++g)
#pragma unroll
        for (int fj = 0; fj < 2; ++fj)
          acc[fj][g] = __builtin_amdgcn_mfma_f32_16x16x32_bf16(af[h], bfr[g][fj][h], acc[fj][g], 0, 0, 0);
    __builtin_amdgcn_s_setprio(0);
    rb = (rb == 2) ? 0 : rb + 1;
    sb = (sb == 2) ? 0 : sb + 1;
  }

  // epilogue
#pragma unroll
  for (int fj = 0; fj < 2; ++fj) {
    const int col = j0 + fj * 16 + lr;
    const float4 bb = bias4[col];
    const int rbase = m0 + wv * 16 + lk * 4;
#pragma unroll
    for (int q = 0; q < 4; ++q) {
      const int row = rbase + q;
      const float r = sigmoidf_(acc[fj][0][q] + bb.x);
      const float z = sigmoidf_(acc[fj][1][q] + bb.y);
      const float n = tanhf(acc[fj][2][q] + bb.z + r * (acc[fj][3][q] + bb.w));
      const float hv = (1.0f - z) * n + z * Hin[(size_t)row * HD + col];
      Hout[(size_t)row * HD + col]  = hv;
      HoutB[(size_t)row * HD + col] = f2b(hv);
    }
  }
}

// ---------------- fused GRU step v6 (round-8, encoder) ----------------
__global__ __launch_bounds__(256, 2)
void gru6(const bf16_t* __restrict__ A1, int lda1, int k1s,
          const bf16_t* __restrict__ Wih, int ldwih,
          const bf16_t* __restrict__ Hb,
          const bf16_t* __restrict__ Whh,
          const float* __restrict__ Hin,
          const float* __restrict__ bih, const float* __restrict__ bhh,
          float* __restrict__ Hout, bf16_t* __restrict__ HoutB)
{
  __shared__ bf16_t aT[3][128 * 64];
  __shared__ bf16_t bT[3][48 * 64];
  const int tid = threadIdx.x, wv = tid >> 6, lane = tid & 63;
  const int bid = blockIdx.x;
  const int xcd = bid & 7, loc = bid >> 3;
  const int j0 = (xcd * 16 + (loc >> 2)) * 16;
  const int m0 = (loc & 3) * 128;
  const int lr = lane & 15, lk = lane >> 4;
  const int rl = lane >> 3;
  const int cl = (lane & 7) * 8;

  fx4 acc[2][4];
#pragma unroll
  for (int m = 0; m < 2; ++m)
#pragma unroll
    for (int g = 0; g < 4; ++g) acc[m][g] = fx4{0.f, 0.f, 0.f, 0.f};

  const bf16_t* A1b = A1 ? A1 : Hb;

  int aOff0[4], aOff1[4], aSlot[4];
#pragma unroll
  for (int i = 0; i < 4; ++i) {
    const int t = wv * 4 + i;
    const int r = t * 8 + rl;
    const int c = cl ^ ((r & 7) * 8);
    aOff0[i] = (m0 + r) * lda1 + c;
    aOff1[i] = (m0 + r) * HD + c;
    aSlot[i] = t * 512;
  }
  const int nB  = (wv < 2) ? 2 : 1;
  const int bt0 = (wv < 2) ? wv * 2 : (2 + wv);
  int bOff0[2], bOff1[2], bSlot[2];
#pragma unroll
  for (int i = 0; i < 2; ++i) {
    const int t = bt0 + (i < nB ? i : 0);
    const int r = t * 8 + rl;
    const int g = r >> 4, jj = r & 15;
    const int c = cl ^ ((r & 7) * 8);
    bOff0[i] = (g * HD + j0 + jj) * ldwih + c;
    bOff1[i] = (g * HD + j0 + jj) * HD + c;
    bSlot[i] = t * 512;
  }
  int aRow[2], bRow[3], ko[2];
#pragma unroll
  for (int m = 0; m < 2; ++m) aRow[m] = (wv * 32 + m * 16 + lr) * 64;
#pragma unroll
  for (int g = 0; g < 3; ++g) bRow[g] = (g * 16 + lr) * 64;
#pragma unroll
  for (int h = 0; h < 2; ++h) ko[h] = (h * 32 + lk * 8) ^ ((lr & 7) * 8);

  auto stage = [&](int buf, int s) {
    const bool p = (s >= k1s);
    const int kb = (p ? (s - k1s) : s) * 64;
    bf16_t* aD = &aT[buf][0];
    bf16_t* bD = &bT[buf][0];
    if (p) {
#pragma unroll
      for (int i = 0; i < 4; ++i) gload16(Hb + aOff1[i] + kb, aD + aSlot[i]);
      gload16(Whh + bOff1[0] + kb, bD + bSlot[0]);
      if (wv < 2) gload16(Whh + bOff1[1] + kb, bD + bSlot[1]);
    } else {
#pragma unroll
      for (int i = 0; i < 4; ++i) gload16(A1b + aOff0[i] + kb, aD + aSlot[i]);
      gload16(Wih + bOff0[0] + kb, bD + bSlot[0]);
      if (wv < 2) gload16(Wih + bOff0[1] + kb, bD + bSlot[1]);
    }
  };

  const int nk = k1s + HD / 64;
  stage(0, 0); stage(1, 1); stage(2, 2);
  int buf = 0;
  for (int s = 0; s < nk; ++s) {
    const int rem = nk - 1 - s;
    if (rem >= 2)      { if (wv < 2) wait_vm12(); else wait_vm10(); }
    else if (rem == 1) { if (wv < 2) wait_vm6();  else wait_vm5();  }
    else               wait_vm0();
    __builtin_amdgcn_s_barrier();
    const bf16_t* aB = &aT[buf][0];
    const bf16_t* bB = &bT[buf][0];
    bfx8 af[2][2], bfr[3][2];
#pragma unroll
    for (int m = 0; m < 2; ++m)
#pragma unroll
      for (int h = 0; h < 2; ++h)
        af[m][h] = *reinterpret_cast<const bfx8*>(&aB[aRow[m] + ko[h]]);
#pragma unroll
    for (int g = 0; g < 3; ++g)
#pragma unroll
      for (int h = 0; h < 2; ++h)
        bfr[g][h] = *reinterpret_cast<const bfx8*>(&bB[bRow[g] + ko[h]]);
    wait_lgkm0();
    __builtin_amdgcn_sched_barrier(0);
    __builtin_amdgcn_s_barrier();
    if (s + 3 < nk) stage(buf, s + 3);
    const bool p = (s >= k1s);
    __builtin_amdgcn_s_setprio(1);
#pragma unroll
    for (int h = 0; h < 2; ++h)
#pragma unroll
      for (int g = 0; g < 3; ++g) {
        const int slot = (g == 2) ? (p ? 3 : 2) : g;
#pragma unroll
        for (int m = 0; m < 2; ++m)
          acc[m][slot] = __builtin_amdgcn_mfma_f32_16x16x32_bf16(af[m][h], bfr[g][h], acc[m][slot], 0, 0, 0);
      }
    __builtin_amdgcn_s_setprio(0);
    buf = (buf == 2) ? 0 : buf + 1;
  }

  const int col = j0 + lr;
  const float br  = bih[col] + bhh[col];
  const float bz  = bih[HD + col] + bhh[HD + col];
  const float bin = bih[2 * HD + col];
  const float bhn = bhh[2 * HD + col];
#pragma unroll
  for (int m = 0; m < 2; ++m) {
    const int rbase = m0 + wv * 32 + m * 16 + lk * 4;
#pragma unroll
    for (int q = 0; q < 4; ++q) {
      const int row = rbase + q;
      const float r = sigmoidf_(acc[m][0][q] + br);
      const float z = sigmoidf_(acc[m][1][q] + bz);
      const float n = tanhf(acc[m][2][q] + bin + r * (acc[m][3][q] + bhn));
      const float hv = (1.0f - z) * n + z * Hin[(size_t)row * HD + col];
      Hout[(size_t)row * HD + col]  = hv;
      HoutB[(size_t)row * HD + col] = f2b(hv);
    }
  }
}

// ---------------- bf16 NT GEMM (counted-vmcnt pipeline, depth-2) ----------------
__global__ __launch_bounds__(256, 2)
void gemm_nt3(const bf16_t* __restrict__ A, int lda, int K,
              const bf16_t* __restrict__ W, int ldw,
              const float* __restrict__ bias,
              float* __restrict__ O, int ldo, int N,
              bf16_t* __restrict__ OB, int ldob)
{
  __shared__ bf16_t aT[2][64 * 64];
  __shared__ bf16_t bT[2][64 * 64];
  const int tid = threadIdx.x, wave = tid >> 6, lane = tid & 63;
  const int m0 = blockIdx.y * 64, n0 = blockIdx.x * 64;
  const int wm = wave & 1, wn = wave >> 1;
  const int lr = lane & 15, lk = lane >> 4;
  const int rl = lane >> 3, cl = (lane & 7) * 8;

  fx4 acc[2][2];
#pragma unroll
  for (int a = 0; a < 2; ++a)
#pragma unroll
    for (int b = 0; b < 2; ++b) acc[a][b] = fx4{0.f, 0.f, 0.f, 0.f};

  const bf16_t* pA[2]; const bf16_t* pB[2]; int slot[2];
#pragma unroll
  for (int i = 0; i < 2; ++i) {
    const int t = wave * 2 + i;
    const int r = t * 8 + rl;
    const int c = cl ^ ((r & 7) * 8);
    pA[i] = A + (size_t)(m0 + r) * lda + c;
    pB[i] = W + (size_t)(n0 + r) * ldw + c;
    slot[i] = t * 512;
  }
  int aRow[2], bRow[2], ko[2];
#pragma unroll
  for (int f = 0; f < 2; ++f) {
    aRow[f] = (wm * 32 + f * 16 + lr) * 64;
    bRow[f] = (wn * 32 + f * 16 + lr) * 64;
  }
#pragma unroll
  for (int h = 0; h < 2; ++h) ko[h] = (h * 32 + lk * 8) ^ ((lr & 7) * 8);

  auto stage = [&](int buf, int kb) {
#pragma unroll
    for (int i = 0; i < 2; ++i) {
      gload16(pA[i] + kb, &aT[buf][slot[i]]);
      gload16(pB[i] + kb, &bT[buf][slot[i]]);
    }
  };

  const int nk = K >> 6;
  stage(0, 0);
  stage(1, 64);
  for (int s = 0; s < nk; ++s) {
    if (s == nk - 1) wait_vm0(); else wait_vm4();
    __builtin_amdgcn_s_barrier();
    const bf16_t* aB = &aT[s & 1][0];
    const bf16_t* bB = &bT[s & 1][0];
    bfx8 af[2][2], bfr[2][2];
#pragma unroll
    for (int f = 0; f < 2; ++f)
#pragma unroll
      for (int h = 0; h < 2; ++h) {
        af[f][h]  = *reinterpret_cast<const bfx8*>(&aB[aRow[f] + ko[h]]);
        bfr[f][h] = *reinterpret_cast<const bfx8*>(&bB[bRow[f] + ko[h]]);
      }
    wait_lgkm0();
    __builtin_amdgcn_sched_barrier(0);
    __builtin_amdgcn_s_barrier();
    if (s + 2 < nk) stage(s & 1, (s + 2) << 6);
    __builtin_amdgcn_s_setprio(1);
#pragma unroll
    for (int h = 0; h < 2; ++h)
#pragma unroll
      for (int fm = 0; fm < 2; ++fm)
#pragma unroll
        for (int fj = 0; fj < 2; ++fj)
          acc[fm][fj] = __builtin_amdgcn_mfma_f32_16x16x32_bf16(af[fm][h], bfr[fj][h], acc[fm][fj], 0, 0, 0);
    __builtin_amdgcn_s_setprio(0);
  }

#pragma unroll
  for (int fm = 0; fm < 2; ++fm)
#pragma unroll
    for (int fj = 0; fj < 2; ++fj) {
      const int col = n0 + wn * 32 + fj * 16 + lr;
      if (col < N) {
        const float bb = bias[col];
#pragma unroll
        for (int q = 0; q < 4; ++q) {
          const int row = m0 + wm * 32 + fm * 16 + lk * 4 + q;
          const float v = acc[fm][fj][q] + bb;
          O[(size_t)row * ldo + col] = v;
          if (OB) OB[(size_t)row * ldob + col] = f2b(v);
        }
      }
    }
}

// ---------------- z build (writes bf16) ----------------
__global__ void build_zb(const float* __restrict__ mu, const float* __restrict__ lv,
                         const float* __restrict__ eps, const float* __restrict__ genre,
                         bf16_t* __restrict__ zb) {
  int i = blockIdx.x * 256 + threadIdx.x;
  int b = i >> 10, c = i & 1023;
  float v;
  if (c < LATM) {
    size_t k = (size_t)b * LATM + c;
    v = mu[k] + expf(0.5f * lv[k]) * eps[k];
  } else {
    v = genre[b * NGENRE + (c - LATM)];
  }
  zb[i] = f2b(v);
}

// ================= fp32 fallback =================
__global__ __launch_bounds__(256, 1)
void gru_stepF(const float* __restrict__ A1, int lda1, int K1,
               const float* __restrict__ Wih,
               const float* __restrict__ Hin,
               const float* __restrict__ Whh,
               const float* __restrict__ bih, const float* __restrict__ bhh,
               float* __restrict__ Hout)
{
  __shared__ bf16_t a_lds[128][32];
  __shared__ bf16_t b_lds[96][32];
  const int tid = threadIdx.x, wave = tid >> 6, lane = tid & 63;
  const int m0 = (blockIdx.x >> 6) * 128, j0 = (blockIdx.x & 63) * 32;
  const int lr = lane & 15, lk = lane >> 4;
  fx4 acc[2][2][4];
#pragma unroll
  for (int a = 0; a < 2; ++a)
#pragma unroll
    for (int b = 0; b < 2; ++b)
#pragma unroll
      for (int g = 0; g < 4; ++g) acc[a][b][g] = fx4{0.f, 0.f, 0.f, 0.f};

  for (int ph = 0; ph < 2; ++ph) {
    const float* Ag = ph ? Hin : A1;
    const int lda = ph ? HD : lda1, kLen = ph ? HD : K1;
    const float* W = ph ? Whh : Wih;
    const int nslot = ph ? 3 : 2;
    const int nkk = (kLen + 31) >> 5;
    for (int s = 0; s < nkk; ++s) {
      const int kb = s << 5;
#pragma unroll
      for (int it = 0; it < 16; ++it) {
        int i = tid + it * 256;
        int r = i >> 5, kk = i & 31, gk = kb + kk;
        float v = 0.0f;
        if (Ag && gk < kLen) v = Ag[(size_t)(m0 + r) * lda + gk];
        a_lds[r][kk] = f2b(v);
      }
#pragma unroll
      for (int it = 0; it < 12; ++it) {
        int i = tid + it * 256;
        int r = i >> 5, kk = i & 31, g = r >> 5, jj = r & 31, gk = kb + kk;
        b_lds[r][kk] = (gk < kLen) ? f2b(W[(size_t)(g * HD + j0 + jj) * kLen + gk]) : f2b(0.0f);
      }
      __syncthreads();
      bfx8 af[2];
#pragma unroll
      for (int fm = 0; fm < 2; ++fm)
        af[fm] = *reinterpret_cast<const bfx8*>(&a_lds[wave * 32 + fm * 16 + lr][lk * 8]);
#pragma unroll
      for (int g = 0; g < 3; ++g) {
        const int slot = (g == 2) ? nslot : g;
#pragma unroll
        for (int fj = 0; fj < 2; ++fj) {
          bfx8 bfr = *reinterpret_cast<const bfx8*>(&b_lds[g * 32 + fj * 16 + lr][lk * 8]);
#pragma unroll
          for (int fm = 0; fm < 2; ++fm)
            acc[fm][fj][slot] = __builtin_amdgcn_mfma_f32_16x16x32_bf16(af[fm], bfr, acc[fm][fj][slot], 0, 0, 0);
        }
      }
      __syncthreads();
    }
  }
#pragma unroll
  for (int fj = 0; fj < 2; ++fj) {
    const int col = j0 + fj * 16 + lr;
    const float br = bih[col] + bhh[col];
    const float bz = bih[HD + col] + bhh[HD + col];
    const float bin = bih[2 * HD + col];
    const float bhn = bhh[2 * HD + col];
#pragma unroll
    for (int fm = 0; fm < 2; ++fm) {
      const int rbase = m0 + wave * 32 + fm * 16 + lk * 4;
#pragma unroll
      for (int q = 0; q < 4; ++q) {
        const int row = rbase + q;
        const float r = sigmoidf_(acc[fm][fj][0][q] + br);
        const float z = sigmoidf_(acc[fm][fj][1][q] + bz);
        const float n = tanhf(acc[fm][fj][2][q] + bin + r * (acc[fm][fj][3][q] + bhn));
        Hout[(size_t)row * HD + col] = (1.0f - z) * n + z * Hin[(size_t)row * HD + col];
      }
    }
  }
}

__global__ __launch_bounds__(256, 1)
void gemm_ntF(const float* __restrict__ A, int lda, int K,
              const float* __restrict__ W,
              const float* __restrict__ bias,
              float* __restrict__ O, int ldo, int N)
{
  __shared__ bf16_t a_lds[64][32];
  __shared__ bf16_t b_lds[64][32];
  const int tid = threadIdx.x, wave = tid >> 6, lane = tid & 63;
  const int m0 = blockIdx.y * 64, n0 = blockIdx.x * 64;
  const int wm = (wave & 1) * 32, wn = (wave >> 1) * 32;
  const int lr = lane & 15, lk = lane >> 4;
  fx4 acc[2][2];
#pragma unroll
  for (int a = 0; a < 2; ++a)
#pragma unroll
    for (int b = 0; b < 2; ++b) acc[a][b] = fx4{0.f, 0.f, 0.f, 0.f};
  for (int kb = 0; kb < K; kb += 32) {
#pragma unroll
    for (int it = 0; it < 8; ++it) {
      int i = tid + it * 256;
      int r = i >> 5, kk = i & 31;
      a_lds[r][kk] = f2b(A[(size_t)(m0 + r) * lda + kb + kk]);
    }
#pragma unroll
    for (int it = 0; it < 8; ++it) {
      int i = tid + it * 256;
      int r = i >> 5, kk = i & 31;
      int n = n0 + r;
      b_lds[r][kk] = (n < N) ? f2b(W[(size_t)n * K + kb + kk]) : f2b(0.0f);
    }
    __syncthreads();
    bfx8 af[2], bfr[2];
#pragma unroll
    for (int f = 0; f < 2; ++f) {
      af[f] = *reinterpret_cast<const bfx8*>(&a_lds[wm + f * 16 + lr][lk * 8]);
      bfr[f] = *reinterpret_cast<const bfx8*>(&b_lds[wn + f * 16 + lr][lk * 8]);
    }
#pragma unroll
    for (int fm = 0; fm < 2; ++fm)
#pragma unroll
      for (int fj = 0; fj < 2; ++fj)
        acc[fm][fj] = __builtin_amdgcn_mfma_f32_16x16x32_bf16(af[fm], bfr[fj], acc[fm][fj], 0, 0, 0);
    __syncthreads();
  }
#pragma unroll
  for (int fm = 0; fm < 2; ++fm)
#pragma unroll
    for (int fj = 0; fj < 2; ++fj) {
      const int col = n0 + wn + fj * 16 + lr;
      if (col < N) {
        const float bb = bias[col];
#pragma unroll
        for (int q = 0; q < 4; ++q) {
          const int row = m0 + wm + fm * 16 + lk * 4 + q;
          O[(size_t)row * ldo + col] = acc[fm][fj][q] + bb;
        }
      }
    }
}

__global__ void build_zf(const float* __restrict__ mu, const float* __restrict__ lv,
                         const float* __restrict__ eps, const float* __restrict__ genre,
                         float* __restrict__ z) {
  int i = blockIdx.x * 256 + threadIdx.x;
  int b = i >> 10, c = i & 1023;
  z[i] = (c < LATM) ? mu[(size_t)b * LATM + c] + expf(0.5f * lv[(size_t)b * LATM + c]) * eps[(size_t)b * LATM + c]
                    : genre[b * NGENRE + (c - LATM)];
}

// ---------------- host ----------------
extern "C" void kernel_launch(void* const* d_in, const int* in_sizes, int n_in,
                              void* d_out, int out_size, void* d_ws, size_t ws_size,
                              hipStream_t stream) {
  const float* x      = (const float*)d_in[0];
  const float* genre  = (const float*)d_in[1];
  const float* eps    = (const float*)d_in[2];
  const float* eWih   = (const float*)d_in[3];
  const float* eWhh   = (const float*)d_in[4];
  const float* eBih   = (const float*)d_in[5];
  const float* eBhh   = (const float*)d_in[6];
  const float* dWih   = (const float*)d_in[7];
  const float* dWhh   = (const float*)d_in[8];
  const float* dBih   = (const float*)d_in[9];
  const float* dBhh   = (const float*)d_in[10];
  const float* fcMuW  = (const float*)d_in[11];
  const float* fcMuB  = (const float*)d_in[12];
  const float* fcLvW  = (const float*)d_in[13];
  const float* fcLvB  = (const float*)d_in[14];
  const float* fcOutW = (const float*)d_in[15];
  const float* fcOutB = (const float*)d_in[16];
  const float* fcDecW = (const float*)d_in[17];
  const float* fcDecB = (const float*)d_in[18];

  float* out = (float*)d_out;
  float* muO = out + (size_t)TT * BB * INDIM;
  float* lvO = muO + (size_t)BB * LATM;

  const size_t nEih = (size_t)3 * HD * XKP;
  const size_t nEhh = (size_t)3 * HD * HD;
  const size_t nDih = (size_t)3 * HD * INDIM;
  const size_t nDhh = (size_t)3 * HD * HD;
  const size_t nMu  = (size_t)1024 * HD;
  const size_t nOut = (size_t)HD * LATD;
  const size_t nDec = (size_t)INDIM * HD;
  const size_t oEih = 0;
  const size_t oEhh = oEih + nEih;
  const size_t oDih = oEhh + nEhh;
  const size_t oDhh = oDih + nDih;
  const size_t oMu  = oDhh + nDhh;
  const size_t oLv  = oMu + nMu;
  const size_t oOut = oLv + nMu;
  const size_t oDec = oOut + nOut;
  const size_t wTot = oDec + nDec;

  const size_t bytesW  = wTot * 2;
  const size_t bytesHF = (size_t)BB * HD * 4;
  const size_t bytesHB = (size_t)BB * HD * 2;
  const size_t bytesZB = (size_t)BB * LATD * 2;
  const size_t bytesNB = (size_t)BB * INDIM * 2;
  const size_t bytesX1 = (size_t)BB * XKP * 2;
  const size_t bytesXB = (size_t)TT * BB * XKP * 2;
  const size_t needB = bytesW + 2 * bytesHF + 2 * bytesHB + bytesZB + bytesNB + bytesX1 + 1024;
  const size_t needA = needB + bytesXB;
  // composed-decoder tier extras
  const size_t bytesWdT  = (size_t)HD * 512 * 2;
  const size_t bytesWcB  = (size_t)3 * HD * HD * 2;
  const size_t bytesWcF  = (size_t)3 * HD * HD * 4;
  const size_t bytesWp   = (size_t)4 * HD * HD * 2;
  const size_t bytesBc   = (size_t)3 * HD * 4;
  const size_t bytesB4   = (size_t)HD * 16;
  const size_t bytesZero = (size_t)HD * 4;
  const size_t bytesHist = (size_t)CHUNK * BB * HD * 2;
  const size_t needC = needA + bytesWdT + bytesWcB + bytesWcF + 2 * bytesWp +
                       bytesBc + 2 * bytesB4 + bytesZero + bytesHist + 1024;

  if (ws_size >= needB) {
    const bool haveXB = (ws_size >= needA);
    const bool haveCP = (ws_size >= needC);
    char* p = (char*)d_ws;
    bf16_t* wb = (bf16_t*)p;            p += bytesW;
    float* h0  = (float*)p;             p += bytesHF;
    float* h1  = (float*)p;             p += bytesHF;
    bf16_t* hb0 = (bf16_t*)p;           p += bytesHB;
    bf16_t* hb1 = (bf16_t*)p;           p += bytesHB;
    bf16_t* zb  = (bf16_t*)p;           p += bytesZB;
    bf16_t* nb  = (bf16_t*)p;           p += bytesNB;
    bf16_t* x1  = (bf16_t*)p;           p += bytesX1;
    bf16_t* xb  = haveXB ? (bf16_t*)p : nullptr;
    if (haveXB) p += bytesXB;
    bf16_t *wdT = nullptr, *wcB = nullptr, *wP = nullptr, *wP0 = nullptr, *hist = nullptr;
    float *wcF = nullptr, *bc = nullptr, *zerosb = nullptr;
    float4 *b4D = nullptr, *b4D0 = nullptr;
    if (haveCP) {
      wdT = (bf16_t*)p;  p += bytesWdT;
      wcB = (bf16_t*)p;  p += bytesWcB;
      wP  = (bf16_t*)p;  p += bytesWp;
      wP0 = (bf16_t*)p;  p += bytesWp;
      wcF = (float*)p;   p += bytesWcF;
      bc  = (float*)p;   p += bytesBc;
      b4D = (float4*)p;  p += bytesB4;
      b4D0 = (float4*)p; p += bytesB4;
      zerosb = (float*)p; p += bytesZero;
      hist = (bf16_t*)p; p += bytesHist;
    }

    auto cast = [&](const float* s, bf16_t* d, int rs, int rp, int K, int ldp) {
      int g = rp > 8192 ? 8192 : rp;
      wcast_pad<<<g, 256, 0, stream>>>(s, d, rs, rp, K, ldp);
    };
    cast(eWih,   wb + oEih, 3 * HD, 3 * HD, XK,    XKP);
    cast(eWhh,   wb + oEhh, 3 * HD, 3 * HD, HD,    HD);
    cast(dWih,   wb + oDih, 3 * HD, 3 * HD, INDIM, INDIM);
    cast(dWhh,   wb + oDhh, 3 * HD, 3 * HD, HD,    HD);
    cast(fcMuW,  wb + oMu,  LATM,   1024,   HD,    HD);
    cast(fcLvW,  wb + oLv,  LATM,   1024,   HD,    HD);
    cast(fcOutW, wb + oOut, HD,     HD,     LATD,  LATD);
    cast(fcDecW, wb + oDec, INDIM,  INDIM,  HD,    HD);
    if (haveXB) cast(x, xb, TT * BB, TT * BB, XK, XKP);

    if (haveCP) {
      // decoder weight composition
      hipMemsetAsync(zerosb, 0, bytesZero, stream);
      wtransp<<<(HD * 512) / 256, 256, 0, stream>>>(fcDecW, wdT);
      gemm_nt3<<<dim3(HD / 64, (3 * HD) / 64), 256, 0, stream>>>(
          wb + oDih, INDIM, INDIM, wdT, INDIM, zerosb, wcF, HD, HD, wcB, HD);
      bcomp<<<(3 * HD) / 256, 256, 0, stream>>>(dWih, fcDecB, bc);
      biasbuild<<<HD / 256, 256, 0, stream>>>(bc, dBih, dBhh, b4D, b4D0);
      wprime<<<4096, 256, 0, stream>>>(wcB, wb + oDhh, wP, wP0);
    }

    hipMemsetAsync(h0, 0, bytesHF, stream);
    hipMemsetAsync(hb0, 0, bytesHB, stream);

    float*  hF[2] = {h0, h1};
    bf16_t* hB[2] = {hb0, hb1};

    // ---- encoder ----
    for (int t = 0; t < TT; ++t) {
      const int ci = t & 1, co = ci ^ 1;
      const bf16_t* xt;
      if (haveXB) {
        xt = xb + (size_t)t * BB * XKP;
      } else {
        wcast_pad<<<512, 256, 0, stream>>>(x + (size_t)t * BB * XK, x1, BB, BB, XK, XKP);
        xt = x1;
      }
      gru6<<<512, 256, 0, stream>>>(xt, XKP, XKP / 64,
                                    wb + oEih, XKP, hB[ci], wb + oEhh,
                                    hF[ci], eBih, eBhh, hF[co], hB[co]);
    }
    // h_enc = hF[0]/hB[0]
    gemm_nt3<<<dim3(16, 8), 256, 0, stream>>>(hB[0], HD, HD, wb + oMu, HD, fcMuB,
                                              muO, LATM, LATM, nullptr, 0);
    gemm_nt3<<<dim3(16, 8), 256, 0, stream>>>(hB[0], HD, HD, wb + oLv, HD, fcLvB,
                                              lvO, LATM, LATM, nullptr, 0);
    build_zb<<<(BB * LATD) / 256, 256, 0, stream>>>(muO, lvO, eps, genre, zb);
    gemm_nt3<<<dim3(32, 8), 256, 0, stream>>>(zb, LATD, LATD, wb + oOut, LATD, fcOutB,
                                              hF[0], HD, HD, hB[0], HD);
    // ---- decoder ----
    if (haveCP) {
      for (int t = 0; t < TT; ++t) {
        const bf16_t* hprev = (t == 0) ? hB[0] : hist + (size_t)((t - 1) & (CHUNK - 1)) * BB * HD;
        gruC<<<512, 256, 0, stream>>>(hprev, t ? wP : wP0, t ? b4D : b4D0,
                                      hF[t & 1], hF[(t & 1) ^ 1],
                                      hist + (size_t)(t & (CHUNK - 1)) * BB * HD);
        if ((t & (CHUNK - 1)) == CHUNK - 1) {
          gemm_nt3<<<dim3(INDIM / 64, (CHUNK * BB) / 64), 256, 0, stream>>>(
              hist, HD, HD, wb + oDec, HD, fcDecB,
              out + (size_t)(t - (CHUNK - 1)) * BB * INDIM, INDIM, INDIM, nullptr, 0);
        }
      }
    } else {
      for (int t = 0; t < TT; ++t) {
        const int ci = t & 1, co = ci ^ 1;
        gru6<<<512, 256, 0, stream>>>(t ? nb : (const bf16_t*)nullptr, INDIM,
                                      t ? INDIM / 64 : 0,
                                      wb + oDih, INDIM, hB[ci], wb + oDhh,
                                      hF[ci], dBih, dBhh, hF[co], hB[co]);
        gemm_nt3<<<dim3(8, 8), 256, 0, stream>>>(hB[co], HD, HD, wb + oDec, HD, fcDecB,
                                                 out + (size_t)t * BB * INDIM, INDIM, INDIM,
                                                 nb, INDIM);
      }
    }
  } else {
    // ---- fp32 fallback ----
    float* h0 = (float*)d_ws;
    float* h1 = h0 + (size_t)BB * HD;
    float* zb = h1 + (size_t)BB * HD;
    hipMemsetAsync(h0, 0, (size_t)BB * HD * sizeof(float), stream);
    float* hF[2] = {h0, h1};
    for (int t = 0; t < TT; ++t) {
      const int ci = t & 1, co = ci ^ 1;
      gru_stepF<<<256, 256, 0, stream>>>(x + (size_t)t * BB * XK, XK, XK, eWih,
                                         hF[ci], eWhh, eBih, eBhh, hF[co]);
    }
    gemm_ntF<<<dim3(16, 8), 256, 0, stream>>>(hF[0], HD, HD, fcMuW, fcMuB, muO, LATM, LATM);
    gemm_ntF<<<dim3(16, 8), 256, 0, stream>>>(hF[0], HD, HD, fcLvW, fcLvB, lvO, LATM, LATM);
    build_zf<<<(BB * LATD) / 256, 256, 0, stream>>>(muO, lvO, eps, genre, zb);
    gemm_ntF<<<dim3(32, 8), 256, 0, stream>>>(zb, LATD, LATD, fcOutW, fcOutB, hF[0], HD, HD);
    for (int t = 0; t < TT; ++t) {
      const int ci = t & 1, co = ci ^ 1;
      gru_stepF<<<256, 256, 0, stream>>>(t ? out + (size_t)(t - 1) * BB * INDIM : nullptr,
                                         INDIM, INDIM, dWih, hF[ci], dWhh, dBih, dBhh, hF[co]);
      gemm_ntF<<<dim3(8, 8), 256, 0, stream>>>(hF[co], HD, HD, fcDecW, fcDecB,
                                               out + (size_t)t * BB * INDIM, INDIM, INDIM);
    }
  }
  (void)in_sizes; (void)n_in; (void)out_size;
}

// Round 10
// 17044.588 us; speedup vs baseline: 1.9933x; 1.0043x over previous
//
#include <hip/hip_runtime.h>
#include <hip/hip_bf16.h>

typedef __bf16 bf16_t;
typedef bf16_t bfx8 __attribute__((ext_vector_type(8)));
typedef float  fx4  __attribute__((ext_vector_type(4)));

#define TT     256
#define BB     512
#define INDIM  512
#define NGENRE 5
#define HD     2048
#define LATD   1024
#define LATM   1019
#define XK     517
#define XKP    576
#define CHUNK  64
#define GIW    6144

// ---------------- helpers ----------------
__device__ __forceinline__ bf16_t f2b(float f) {
  unsigned u = __builtin_bit_cast(unsigned, f);
  u += 0x7fffu + ((u >> 16) & 1u);
  unsigned short s = (unsigned short)(u >> 16);
  return __builtin_bit_cast(bf16_t, s);
}
__device__ __forceinline__ float sigmoidf_(float x) { return 1.0f / (1.0f + __expf(-x)); }

__device__ __forceinline__ void gload16(const bf16_t* g, bf16_t* l) {
  __builtin_amdgcn_global_load_lds((const __attribute__((address_space(1))) void*)g,
                                   (__attribute__((address_space(3))) void*)l,
                                   16, 0, 0);
}
__device__ __forceinline__ void wait_vm0()  { asm volatile("s_waitcnt vmcnt(0)" ::: "memory"); }
__device__ __forceinline__ void wait_vm4()  { asm volatile("s_waitcnt vmcnt(4)" ::: "memory"); }
__device__ __forceinline__ void wait_vm5()  { asm volatile("s_waitcnt vmcnt(5)" ::: "memory"); }
__device__ __forceinline__ void wait_vm6()  { asm volatile("s_waitcnt vmcnt(6)" ::: "memory"); }
__device__ __forceinline__ void wait_vm10() { asm volatile("s_waitcnt vmcnt(10)" ::: "memory"); }
__device__ __forceinline__ void wait_vm12() { asm volatile("s_waitcnt vmcnt(12)" ::: "memory"); }
__device__ __forceinline__ void wait_lgkm0() { asm volatile("s_waitcnt lgkmcnt(0)" ::: "memory"); }

// ---------------- fp32 -> bf16 cast with row/col zero-padding ----------------
__global__ void wcast_pad(const float* __restrict__ src, bf16_t* __restrict__ dst,
                          int rows_src, int rows_pad, int K, int ldp) {
  for (int r = blockIdx.x; r < rows_pad; r += gridDim.x)
    for (int c = threadIdx.x; c < ldp; c += 256)
      dst[(size_t)r * ldp + c] = (r < rows_src && c < K) ? f2b(src[(size_t)r * K + c]) : f2b(0.0f);
}

// ---------------- small prep kernels (decoder composition) ----------------
__global__ void wtransp(const float* __restrict__ src, bf16_t* __restrict__ dst) {
  int i = blockIdx.x * 256 + threadIdx.x;     // over 2048*512
  int r = i >> 9, c = i & 511;
  dst[i] = f2b(src[(size_t)c * 2048 + r]);
}
__global__ void bcomp(const float* __restrict__ wih, const float* __restrict__ bdec,
                      float* __restrict__ bc) {
  int r = blockIdx.x * 256 + threadIdx.x;
  if (r >= 3 * HD) return;
  float s = 0.f;
  for (int k = 0; k < 512; ++k) s += wih[(size_t)r * 512 + k] * bdec[k];
  bc[r] = s;
}
__global__ void biasbuild(const float* __restrict__ bc, const float* __restrict__ bih,
                          const float* __restrict__ bhh,
                          float4* __restrict__ bD, float4* __restrict__ bD0) {
  int c = blockIdx.x * 256 + threadIdx.x;
  if (c >= HD) return;
  float r0 = bih[c] + bhh[c];
  float z0 = bih[HD + c] + bhh[HD + c];
  float i0 = bih[2 * HD + c];
  float h0 = bhh[2 * HD + c];
  bD0[c] = float4{r0, z0, i0, h0};
  bD[c]  = float4{r0 + bc[c], z0 + bc[HD + c], i0 + bc[2 * HD + c], h0};
}
__global__ void wprime(const bf16_t* __restrict__ wc, const bf16_t* __restrict__ whh,
                       bf16_t* __restrict__ wp, bf16_t* __restrict__ wp0) {
  const size_t total = (size_t)4 * HD * HD;
  for (size_t i = (size_t)blockIdx.x * 256 + threadIdx.x; i < total; i += (size_t)gridDim.x * 256) {
    int row = (int)(i >> 11), k = (int)(i & 2047);
    int g = row >> 11, j = row & 2047;
    bf16_t v, v0;
    if (g == 0) {
      float a = (float)wc[(size_t)j * HD + k], b = (float)whh[(size_t)j * HD + k];
      v = f2b(a + b); v0 = whh[(size_t)j * HD + k];
    } else if (g == 1) {
      size_t o = (size_t)(HD + j) * HD + k;
      v = f2b((float)wc[o] + (float)whh[o]); v0 = whh[o];
    } else if (g == 2) {
      v = wc[(size_t)(2 * HD + j) * HD + k]; v0 = f2b(0.0f);
    } else {
      v = whh[(size_t)(2 * HD + j) * HD + k]; v0 = v;
    }
    wp[i] = v; wp0[i] = v0;
  }
}

// ---------------- composed decoder GRU v2: gate-per-wave split ----------------
// Block 64 rows x 32 j (x4 gates), 256 thr; wave wv owns gate wv for all 64 rows.
// Per wave/iter: 12 ds_read (8 A dup + 4 B unique) : 16 MFMA (vs gruC 18:16).
// Once-per-step LDS gate exchange in epilogue. 1 barrier/iter, 3 bufs, vm6.
__global__ __launch_bounds__(256, 2)
void gruC2(const bf16_t* __restrict__ Hb,
           const bf16_t* __restrict__ Wp,          // 8192 x 2048
           const float4* __restrict__ bias4,
           const float* __restrict__ Hin,
           float* __restrict__ Hout, bf16_t* __restrict__ HoutB)
{
  __shared__ bf16_t aT[3][64 * 64];
  __shared__ bf16_t bT[3][128 * 64];
  const int tid = threadIdx.x, wv = tid >> 6, lane = tid & 63;
  const int bid = blockIdx.x;
  const int j0 = (bid & 63) * 32;
  const int m0 = (bid >> 6) * 64;
  const int lr = lane & 15, lk = lane >> 4;
  const int rl = lane >> 3;
  const int cl = (lane & 7) * 8;

  fx4 acc[4][2];   // [mfrag][fj] for gate wv
#pragma unroll
  for (int m = 0; m < 4; ++m)
#pragma unroll
    for (int fj = 0; fj < 2; ++fj) acc[m][fj] = fx4{0.f, 0.f, 0.f, 0.f};

  int aOff[2], aSlot[2];
#pragma unroll
  for (int i = 0; i < 2; ++i) {
    const int t = wv * 2 + i;              // 0..7
    const int r = t * 8 + rl;              // 0..63
    const int c = cl ^ ((r & 7) * 8);
    aOff[i] = (m0 + r) * HD + c;
    aSlot[i] = t * 512;
  }
  int bOff[4], bSlot[4];
#pragma unroll
  for (int i = 0; i < 4; ++i) {
    const int t = wv * 4 + i;              // 0..15
    const int r = t * 8 + rl;              // 0..127
    const int g = r >> 5, jj = r & 31;
    const int c = cl ^ ((r & 7) * 8);
    bOff[i] = (g * HD + j0 + jj) * HD + c;
    bSlot[i] = t * 512;
  }
  int aRow[4], bRow[2], ko[2];
#pragma unroll
  for (int m = 0; m < 4; ++m) aRow[m] = (m * 16 + lr) * 64;
#pragma unroll
  for (int fj = 0; fj < 2; ++fj) bRow[fj] = (wv * 32 + fj * 16 + lr) * 64;
#pragma unroll
  for (int h = 0; h < 2; ++h) ko[h] = (h * 32 + lk * 8) ^ ((lr & 7) * 8);

  auto stage = [&](int buf, int s) {
    const int kb = s * 64;
#pragma unroll
    for (int i = 0; i < 2; ++i) gload16(Hb + aOff[i] + kb, &aT[buf][aSlot[i]]);
#pragma unroll
    for (int i = 0; i < 4; ++i) gload16(Wp + bOff[i] + kb, &bT[buf][bSlot[i]]);
  };

  const int nk = HD / 64;                  // 32
  stage(0, 0); stage(1, 1);
  int rb = 0, sb = 2;
  for (int s = 0; s < nk; ++s) {
    if (s == nk - 1) wait_vm0(); else wait_vm6();
    __builtin_amdgcn_s_barrier();
    if (s + 2 < nk) stage(sb, s + 2);
    const bf16_t* aB = &aT[rb][0];
    const bf16_t* bB = &bT[rb][0];
    bfx8 af[4][2], bfr[2][2];
#pragma unroll
    for (int m = 0; m < 4; ++m)
#pragma unroll
      for (int h = 0; h < 2; ++h)
        af[m][h] = *reinterpret_cast<const bfx8*>(&aB[aRow[m] + ko[h]]);
#pragma unroll
    for (int fj = 0; fj < 2; ++fj)
#pragma unroll
      for (int h = 0; h < 2; ++h)
        bfr[fj][h] = *reinterpret_cast<const bfx8*>(&bB[bRow[fj] + ko[h]]);
    wait_lgkm0();
    __builtin_amdgcn_sched_barrier(0);
    __builtin_amdgcn_s_setprio(1);
#pragma unroll
    for (int h = 0; h < 2; ++h)
#pragma unroll
      for (int m = 0; m < 4; ++m)
#pragma unroll
        for (int fj = 0; fj < 2; ++fj)
          acc[m][fj] = __builtin_amdgcn_mfma_f32_16x16x32_bf16(af[m][h], bfr[fj][h], acc[m][fj], 0, 0, 0);
    __builtin_amdgcn_s_setprio(0);
    rb = (rb == 2) ? 0 : rb + 1;
    sb = (sb == 2) ? 0 : sb + 1;
  }

  // ---- epilogue: gate exchange + h update ----
  __syncthreads();                          // all reads of bT done
  float* eL = (float*)&bT[0][0];            // [4][64][33] fp32 = 33.8 KB
#pragma unroll
  for (int m = 0; m < 4; ++m)
#pragma unroll
    for (int fj = 0; fj < 2; ++fj)
#pragma unroll
      for (int q = 0; q < 4; ++q)
        eL[((wv * 64 + m * 16 + lk * 4 + q) * 33 + fj * 16 + lr)] = acc[m][fj][q];
  __syncthreads();
  const int col = lane & 31;
  const int rh  = lane >> 5;
  const float4 bb = bias4[j0 + col];
#pragma unroll
  for (int i = 0; i < 8; ++i) {
    const int rowL = wv * 16 + rh * 8 + i;
    const float e0 = eL[((0 * 64 + rowL) * 33 + col)];
    const float e1 = eL[((1 * 64 + rowL) * 33 + col)];
    const float e2 = eL[((2 * 64 + rowL) * 33 + col)];
    const float e3 = eL[((3 * 64 + rowL) * 33 + col)];
    const float r = sigmoidf_(e0 + bb.x);
    const float z = sigmoidf_(e1 + bb.y);
    const float n = tanhf(e2 + bb.z + r * (e3 + bb.w));
    const size_t o = (size_t)(m0 + rowL) * HD + j0 + col;
    const float hv = (1.0f - z) * n + z * Hin[o];
    Hout[o]  = hv;
    HoutB[o] = f2b(hv);
  }
}

// ---------------- encoder GRU with precomputed gi: pure h-recurrence ----------
// Block 64 rows x 32 j (x3 gates), 256 thr, waves 2m x 2colhalf.
// K=2048 (32 iters), acc slots r(init gi_r), z(init gi_z), hn(init 0).
__global__ __launch_bounds__(256, 2)
void gruE(const bf16_t* __restrict__ gi,     // [512][6144], t-slice
          const bf16_t* __restrict__ Hb,
          const bf16_t* __restrict__ Whh,    // [3H][HD] bf16
          const float* __restrict__ Hin,
          const float* __restrict__ bih, const float* __restrict__ bhh,
          float* __restrict__ Hout, bf16_t* __restrict__ HoutB)
{
  __shared__ bf16_t aT[3][64 * 64];
  __shared__ bf16_t bT[3][96 * 64];
  const int tid = threadIdx.x, wv = tid >> 6, lane = tid & 63;
  const int mh = wv >> 1, ch = wv & 1;
  const int bid = blockIdx.x;
  const int j0 = (bid & 63) * 32;
  const int m0 = (bid >> 6) * 64;
  const int lr = lane & 15, lk = lane >> 4;
  const int rl = lane >> 3;
  const int cl = (lane & 7) * 8;
  const int colG = j0 + ch * 16 + lr;

  fx4 acc[2][3];   // [mfrag][r,z,hn]
#pragma unroll
  for (int m = 0; m < 2; ++m) {
#pragma unroll
    for (int q = 0; q < 4; ++q) {
      const int row = m0 + mh * 32 + m * 16 + lk * 4 + q;
      acc[m][0][q] = (float)gi[(size_t)row * GIW + colG];
      acc[m][1][q] = (float)gi[(size_t)row * GIW + 2048 + colG];
      acc[m][2][q] = 0.0f;
    }
  }

  int aOff[2], aSlot[2];
#pragma unroll
  for (int i = 0; i < 2; ++i) {
    const int t = wv * 2 + i;              // 0..7
    const int r = t * 8 + rl;              // 0..63
    const int c = cl ^ ((r & 7) * 8);
    aOff[i] = (m0 + r) * HD + c;
    aSlot[i] = t * 512;
  }
  int bOff[3], bSlot[3];
#pragma unroll
  for (int i = 0; i < 3; ++i) {
    const int t = wv * 3 + i;              // 0..11
    const int r = t * 8 + rl;              // 0..95
    const int g = r >> 5, jj = r & 31;
    const int c = cl ^ ((r & 7) * 8);
    bOff[i] = (g * HD + j0 + jj) * HD + c;
    bSlot[i] = t * 512;
  }
  int aRow[2], bRow[3], ko[2];
#pragma unroll
  for (int m = 0; m < 2; ++m) aRow[m] = (mh * 32 + m * 16 + lr) * 64;
#pragma unroll
  for (int g = 0; g < 3; ++g) bRow[g] = (g * 32 + ch * 16 + lr) * 64;
#pragma unroll
  for (int h = 0; h < 2; ++h) ko[h] = (h * 32 + lk * 8) ^ ((lr & 7) * 8);

  auto stage = [&](int buf, int s) {
    const int kb = s * 64;
#pragma unroll
    for (int i = 0; i < 2; ++i) gload16(Hb + aOff[i] + kb, &aT[buf][aSlot[i]]);
#pragma unroll
    for (int i = 0; i < 3; ++i) gload16(Whh + bOff[i] + kb, &bT[buf][bSlot[i]]);
  };

  const int nk = HD / 64;                  // 32
  stage(0, 0); stage(1, 1);
  int rb = 0, sb = 2;
  for (int s = 0; s < nk; ++s) {
    if (s == nk - 1) wait_vm0(); else wait_vm5();
    __builtin_amdgcn_s_barrier();
    if (s + 2 < nk) stage(sb, s + 2);
    const bf16_t* aB = &aT[rb][0];
    const bf16_t* bB = &bT[rb][0];
    bfx8 af[2][2], bfr[3][2];
#pragma unroll
    for (int m = 0; m < 2; ++m)
#pragma unroll
      for (int h = 0; h < 2; ++h)
        af[m][h] = *reinterpret_cast<const bfx8*>(&aB[aRow[m] + ko[h]]);
#pragma unroll
    for (int g = 0; g < 3; ++g)
#pragma unroll
      for (int h = 0; h < 2; ++h)
        bfr[g][h] = *reinterpret_cast<const bfx8*>(&bB[bRow[g] + ko[h]]);
    wait_lgkm0();
    __builtin_amdgcn_sched_barrier(0);
    __builtin_amdgcn_s_setprio(1);
#pragma unroll
    for (int h = 0; h < 2; ++h)
#pragma unroll
      for (int g = 0; g < 3; ++g)
#pragma unroll
        for (int m = 0; m < 2; ++m)
          acc[m][g] = __builtin_amdgcn_mfma_f32_16x16x32_bf16(af[m][h], bfr[g][h], acc[m][g], 0, 0, 0);
    __builtin_amdgcn_s_setprio(0);
    rb = (rb == 2) ? 0 : rb + 1;
    sb = (sb == 2) ? 0 : sb + 1;
  }

  // ---- epilogue ----
  const float br  = bih[colG] + bhh[colG];
  const float bz  = bih[HD + colG] + bhh[HD + colG];
  const float bin = bih[2 * HD + colG];
  const float bhn = bhh[2 * HD + colG];
#pragma unroll
  for (int m = 0; m < 2; ++m) {
#pragma unroll
    for (int q = 0; q < 4; ++q) {
      const int row = m0 + mh * 32 + m * 16 + lk * 4 + q;
      const float gin = (float)gi[(size_t)row * GIW + 4096 + colG];
      const float r = sigmoidf_(acc[m][0][q] + br);
      const float z = sigmoidf_(acc[m][1][q] + bz);
      const float n = tanhf(gin + bin + r * (acc[m][2][q] + bhn));
      const size_t o = (size_t)row * HD + colG;
      const float hv = (1.0f - z) * n + z * Hin[o];
      Hout[o]  = hv;
      HoutB[o] = f2b(hv);
    }
  }
}

// ---------------- fused GRU step v6 (round-8, encoder fallback) ----------------
__global__ __launch_bounds__(256, 2)
void gru6(const bf16_t* __restrict__ A1, int lda1, int k1s,
          const bf16_t* __restrict__ Wih, int ldwih,
          const bf16_t* __restrict__ Hb,
          const bf16_t* __restrict__ Whh,
          const float* __restrict__ Hin,
          const float* __restrict__ bih, const float* __restrict__ bhh,
          float* __restrict__ Hout, bf16_t* __restrict__ HoutB)
{
  __shared__ bf16_t aT[3][128 * 64];
  __shared__ bf16_t bT[3][48 * 64];
  const int tid = threadIdx.x, wv = tid >> 6, lane = tid & 63;
  const int bid = blockIdx.x;
  const int xcd = bid & 7, loc = bid >> 3;
  const int j0 = (xcd * 16 + (loc >> 2)) * 16;
  const int m0 = (loc & 3) * 128;
  const int lr = lane & 15, lk = lane >> 4;
  const int rl = lane >> 3;
  const int cl = (lane & 7) * 8;

  fx4 acc[2][4];
#pragma unroll
  for (int m = 0; m < 2; ++m)
#pragma unroll
    for (int g = 0; g < 4; ++g) acc[m][g] = fx4{0.f, 0.f, 0.f, 0.f};

  const bf16_t* A1b = A1 ? A1 : Hb;

  int aOff0[4], aOff1[4], aSlot[4];
#pragma unroll
  for (int i = 0; i < 4; ++i) {
    const int t = wv * 4 + i;
    const int r = t * 8 + rl;
    const int c = cl ^ ((r & 7) * 8);
    aOff0[i] = (m0 + r) * lda1 + c;
    aOff1[i] = (m0 + r) * HD + c;
    aSlot[i] = t * 512;
  }
  const int nB  = (wv < 2) ? 2 : 1;
  const int bt0 = (wv < 2) ? wv * 2 : (2 + wv);
  int bOff0[2], bOff1[2], bSlot[2];
#pragma unroll
  for (int i = 0; i < 2; ++i) {
    const int t = bt0 + (i < nB ? i : 0);
    const int r = t * 8 + rl;
    const int g = r >> 4, jj = r & 15;
    const int c = cl ^ ((r & 7) * 8);
    bOff0[i] = (g * HD + j0 + jj) * ldwih + c;
    bOff1[i] = (g * HD + j0 + jj) * HD + c;
    bSlot[i] = t * 512;
  }
  int aRow[2], bRow[3], ko[2];
#pragma unroll
  for (int m = 0; m < 2; ++m) aRow[m] = (wv * 32 + m * 16 + lr) * 64;
#pragma unroll
  for (int g = 0; g < 3; ++g) bRow[g] = (g * 16 + lr) * 64;
#pragma unroll
  for (int h = 0; h < 2; ++h) ko[h] = (h * 32 + lk * 8) ^ ((lr & 7) * 8);

  auto stage = [&](int buf, int s) {
    const bool p = (s >= k1s);
    const int kb = (p ? (s - k1s) : s) * 64;
    bf16_t* aD = &aT[buf][0];
    bf16_t* bD = &bT[buf][0];
    if (p) {
#pragma unroll
      for (int i = 0; i < 4; ++i) gload16(Hb + aOff1[i] + kb, aD + aSlot[i]);
      gload16(Whh + bOff1[0] + kb, bD + bSlot[0]);
      if (wv < 2) gload16(Whh + bOff1[1] + kb, bD + bSlot[1]);
    } else {
#pragma unroll
      for (int i = 0; i < 4; ++i) gload16(A1b + aOff0[i] + kb, aD + aSlot[i]);
      gload16(Wih + bOff0[0] + kb, bD + bSlot[0]);
      if (wv < 2) gload16(Wih + bOff0[1] + kb, bD + bSlot[1]);
    }
  };

  const int nk = k1s + HD / 64;
  stage(0, 0); stage(1, 1); stage(2, 2);
  int buf = 0;
  for (int s = 0; s < nk; ++s) {
    const int rem = nk - 1 - s;
    if (rem >= 2)      { if (wv < 2) wait_vm12(); else wait_vm10(); }
    else if (rem == 1) { if (wv < 2) wait_vm6();  else wait_vm5();  }
    else               wait_vm0();
    __builtin_amdgcn_s_barrier();
    const bf16_t* aB = &aT[buf][0];
    const bf16_t* bB = &bT[buf][0];
    bfx8 af[2][2], bfr[3][2];
#pragma unroll
    for (int m = 0; m < 2; ++m)
#pragma unroll
      for (int h = 0; h < 2; ++h)
        af[m][h] = *reinterpret_cast<const bfx8*>(&aB[aRow[m] + ko[h]]);
#pragma unroll
    for (int g = 0; g < 3; ++g)
#pragma unroll
      for (int h = 0; h < 2; ++h)
        bfr[g][h] = *reinterpret_cast<const bfx8*>(&bB[bRow[g] + ko[h]]);
    wait_lgkm0();
    __builtin_amdgcn_sched_barrier(0);
    __builtin_amdgcn_s_barrier();
    if (s + 3 < nk) stage(buf, s + 3);
    const bool p = (s >= k1s);
    __builtin_amdgcn_s_setprio(1);
#pragma unroll
    for (int h = 0; h < 2; ++h)
#pragma unroll
      for (int g = 0; g < 3; ++g) {
        const int slot = (g == 2) ? (p ? 3 : 2) : g;
#pragma unroll
        for (int m = 0; m < 2; ++m)
          acc[m][slot] = __builtin_amdgcn_mfma_f32_16x16x32_bf16(af[m][h], bfr[g][h], acc[m][slot], 0, 0, 0);
      }
    __builtin_amdgcn_s_setprio(0);
    buf = (buf == 2) ? 0 : buf + 1;
  }

  const int col = j0 + lr;
  const float br  = bih[col] + bhh[col];
  const float bz  = bih[HD + col] + bhh[HD + col];
  const float bin = bih[2 * HD + col];
  const float bhn = bhh[2 * HD + col];
#pragma unroll
  for (int m = 0; m < 2; ++m) {
    const int rbase = m0 + wv * 32 + m * 16 + lk * 4;
#pragma unroll
    for (int q = 0; q < 4; ++q) {
      const int row = rbase + q;
      const float r = sigmoidf_(acc[m][0][q] + br);
      const float z = sigmoidf_(acc[m][1][q] + bz);
      const float n = tanhf(acc[m][2][q] + bin + r * (acc[m][3][q] + bhn));
      const float hv = (1.0f - z) * n + z * Hin[(size_t)row * HD + col];
      Hout[(size_t)row * HD + col]  = hv;
      HoutB[(size_t)row * HD + col] = f2b(hv);
    }
  }
}

// ---------------- bf16 NT GEMM (counted-vmcnt pipeline, depth-2) ----------------
__global__ __launch_bounds__(256, 2)
void gemm_nt3(const bf16_t* __restrict__ A, int lda, int K,
              const bf16_t* __restrict__ W, int ldw,
              const float* __restrict__ bias,
              float* __restrict__ O, int ldo, int N,
              bf16_t* __restrict__ OB, int ldob)
{
  __shared__ bf16_t aT[2][64 * 64];
  __shared__ bf16_t bT[2][64 * 64];
  const int tid = threadIdx.x, wave = tid >> 6, lane = tid & 63;
  const int m0 = blockIdx.y * 64, n0 = blockIdx.x * 64;
  const int wm = wave & 1, wn = wave >> 1;
  const int lr = lane & 15, lk = lane >> 4;
  const int rl = lane >> 3, cl = (lane & 7) * 8;

  fx4 acc[2][2];
#pragma unroll
  for (int a = 0; a < 2; ++a)
#pragma unroll
    for (int b = 0; b < 2; ++b) acc[a][b] = fx4{0.f, 0.f, 0.f, 0.f};

  const bf16_t* pA[2]; const bf16_t* pB[2]; int slot[2];
#pragma unroll
  for (int i = 0; i < 2; ++i) {
    const int t = wave * 2 + i;
    const int r = t * 8 + rl;
    const int c = cl ^ ((r & 7) * 8);
    pA[i] = A + (size_t)(m0 + r) * lda + c;
    pB[i] = W + (size_t)(n0 + r) * ldw + c;
    slot[i] = t * 512;
  }
  int aRow[2], bRow[2], ko[2];
#pragma unroll
  for (int f = 0; f < 2; ++f) {
    aRow[f] = (wm * 32 + f * 16 + lr) * 64;
    bRow[f] = (wn * 32 + f * 16 + lr) * 64;
  }
#pragma unroll
  for (int h = 0; h < 2; ++h) ko[h] = (h * 32 + lk * 8) ^ ((lr & 7) * 8);

  auto stage = [&](int buf, int kb) {
#pragma unroll
    for (int i = 0; i < 2; ++i) {
      gload16(pA[i] + kb, &aT[buf][slot[i]]);
      gload16(pB[i] + kb, &bT[buf][slot[i]]);
    }
  };

  const int nk = K >> 6;
  stage(0, 0);
  stage(1, 64);
  for (int s = 0; s < nk; ++s) {
    if (s == nk - 1) wait_vm0(); else wait_vm4();
    __builtin_amdgcn_s_barrier();
    const bf16_t* aB = &aT[s & 1][0];
    const bf16_t* bB = &bT[s & 1][0];
    bfx8 af[2][2], bfr[2][2];
#pragma unroll
    for (int f = 0; f < 2; ++f)
#pragma unroll
      for (int h = 0; h < 2; ++h) {
        af[f][h]  = *reinterpret_cast<const bfx8*>(&aB[aRow[f] + ko[h]]);
        bfr[f][h] = *reinterpret_cast<const bfx8*>(&bB[bRow[f] + ko[h]]);
      }
    wait_lgkm0();
    __builtin_amdgcn_sched_barrier(0);
    __builtin_amdgcn_s_barrier();
    if (s + 2 < nk) stage(s & 1, (s + 2) << 6);
    __builtin_amdgcn_s_setprio(1);
#pragma unroll
    for (int h = 0; h < 2; ++h)
#pragma unroll
      for (int fm = 0; fm < 2; ++fm)
#pragma unroll
        for (int fj = 0; fj < 2; ++fj)
          acc[fm][fj] = __builtin_amdgcn_mfma_f32_16x16x32_bf16(af[fm][h], bfr[fj][h], acc[fm][fj], 0, 0, 0);
    __builtin_amdgcn_s_setprio(0);
  }

#pragma unroll
  for (int fm = 0; fm < 2; ++fm)
#pragma unroll
    for (int fj = 0; fj < 2; ++fj) {
      const int col = n0 + wn * 32 + fj * 16 + lr;
      if (col < N) {
        const float bb = bias[col];
#pragma unroll
        for (int q = 0; q < 4; ++q) {
          const int row = m0 + wm * 32 + fm * 16 + lk * 4 + q;
          const float v = acc[fm][fj][q] + bb;
          if (O)  O[(size_t)row * ldo + col] = v;
          if (OB) OB[(size_t)row * ldob + col] = f2b(v);
        }
      }
    }
}

// ---------------- z build (writes bf16) ----------------
__global__ void build_zb(const float* __restrict__ mu, const float* __restrict__ lv,
                         const float* __restrict__ eps, const float* __restrict__ genre,
                         bf16_t* __restrict__ zb) {
  int i = blockIdx.x * 256 + threadIdx.x;
  int b = i >> 10, c = i & 1023;
  float v;
  if (c < LATM) {
    size_t k = (size_t)b * LATM + c;
    v = mu[k] + expf(0.5f * lv[k]) * eps[k];
  } else {
    v = genre[b * NGENRE + (c - LATM)];
  }
  zb[i] = f2b(v);
}

// ================= fp32 fallback =================
__global__ __launch_bounds__(256, 1)
void gru_stepF(const float* __restrict__ A1, int lda1, int K1,
               const float* __restrict__ Wih,
               const float* __restrict__ Hin,
               const float* __restrict__ Whh,
               const float* __restrict__ bih, const float* __restrict__ bhh,
               float* __restrict__ Hout)
{
  __shared__ bf16_t a_lds[128][32];
  __shared__ bf16_t b_lds[96][32];
  const int tid = threadIdx.x, wave = tid >> 6, lane = tid & 63;
  const int m0 = (blockIdx.x >> 6) * 128, j0 = (blockIdx.x & 63) * 32;
  const int lr = lane & 15, lk = lane >> 4;
  fx4 acc[2][2][4];
#pragma unroll
  for (int a = 0; a < 2; ++a)
#pragma unroll
    for (int b = 0; b < 2; ++b)
#pragma unroll
      for (int g = 0; g < 4; ++g) acc[a][b][g] = fx4{0.f, 0.f, 0.f, 0.f};

  for (int ph = 0; ph < 2; ++ph) {
    const float* Ag = ph ? Hin : A1;
    const int lda = ph ? HD : lda1, kLen = ph ? HD : K1;
    const float* W = ph ? Whh : Wih;
    const int nslot = ph ? 3 : 2;
    const int nkk = (kLen + 31) >> 5;
    for (int s = 0; s < nkk; ++s) {
      const int kb = s << 5;
#pragma unroll
      for (int it = 0; it < 16; ++it) {
        int i = tid + it * 256;
        int r = i >> 5, kk = i & 31, gk = kb + kk;
        float v = 0.0f;
        if (Ag && gk < kLen) v = Ag[(size_t)(m0 + r) * lda + gk];
        a_lds[r][kk] = f2b(v);
      }
#pragma unroll
      for (int it = 0; it < 12; ++it) {
        int i = tid + it * 256;
        int r = i >> 5, kk = i & 31, g = r >> 5, jj = r & 31, gk = kb + kk;
        b_lds[r][kk] = (gk < kLen) ? f2b(W[(size_t)(g * HD + j0 + jj) * kLen + gk]) : f2b(0.0f);
      }
      __syncthreads();
      bfx8 af[2];
#pragma unroll
      for (int fm = 0; fm < 2; ++fm)
        af[fm] = *reinterpret_cast<const bfx8*>(&a_lds[wave * 32 + fm * 16 + lr][lk * 8]);
#pragma unroll
      for (int g = 0; g < 3; ++g) {
        const int slot = (g == 2) ? nslot : g;
#pragma unroll
        for (int fj = 0; fj < 2; ++fj) {
          bfx8 bfr = *reinterpret_cast<const bfx8*>(&b_lds[g * 32 + fj * 16 + lr][lk * 8]);
#pragma unroll
          for (int fm = 0; fm < 2; ++fm)
            acc[fm][fj][slot] = __builtin_amdgcn_mfma_f32_16x16x32_bf16(af[fm], bfr, acc[fm][fj][slot], 0, 0, 0);
        }
      }
      __syncthreads();
    }
  }
#pragma unroll
  for (int fj = 0; fj < 2; ++fj) {
    const int col = j0 + fj * 16 + lr;
    const float br = bih[col] + bhh[col];
    const float bz = bih[HD + col] + bhh[HD + col];
    const float bin = bih[2 * HD + col];
    const float bhn = bhh[2 * HD + col];
#pragma unroll
    for (int fm = 0; fm < 2; ++fm) {
      const int rbase = m0 + wave * 32 + fm * 16 + lk * 4;
#pragma unroll
      for (int q = 0; q < 4; ++q) {
        const int row = rbase + q;
        const float r = sigmoidf_(acc[fm][fj][0][q] + br);
        const float z = sigmoidf_(acc[fm][fj][1][q] + bz);
        const float n = tanhf(acc[fm][fj][2][q] + bin + r * (acc[fm][fj][3][q] + bhn));
        Hout[(size_t)row * HD + col] = (1.0f - z) * n + z * Hin[(size_t)row * HD + col];
      }
    }
  }
}

__global__ __launch_bounds__(256, 1)
void gemm_ntF(const float* __restrict__ A, int lda, int K,
              const float* __restrict__ W,
              const float* __restrict__ bias,
              float* __restrict__ O, int ldo, int N)
{
  __shared__ bf16_t a_lds[64][32];
  __shared__ bf16_t b_lds[64][32];
  const int tid = threadIdx.x, wave = tid >> 6, lane = tid & 63;
  const int m0 = blockIdx.y * 64, n0 = blockIdx.x * 64;
  const int wm = (wave & 1) * 32, wn = (wave >> 1) * 32;
  const int lr = lane & 15, lk = lane >> 4;
  fx4 acc[2][2];
#pragma unroll
  for (int a = 0; a < 2; ++a)
#pragma unroll
    for (int b = 0; b < 2; ++b) acc[a][b] = fx4{0.f, 0.f, 0.f, 0.f};
  for (int kb = 0; kb < K; kb += 32) {
#pragma unroll
    for (int it = 0; it < 8; ++it) {
      int i = tid + it * 256;
      int r = i >> 5, kk = i & 31;
      a_lds[r][kk] = f2b(A[(size_t)(m0 + r) * lda + kb + kk]);
    }
#pragma unroll
    for (int it = 0; it < 8; ++it) {
      int i = tid + it * 256;
      int r = i >> 5, kk = i & 31;
      int n = n0 + r;
      b_lds[r][kk] = (n < N) ? f2b(W[(size_t)n * K + kb + kk]) : f2b(0.0f);
    }
    __syncthreads();
    bfx8 af[2], bfr[2];
#pragma unroll
    for (int f = 0; f < 2; ++f) {
      af[f] = *reinterpret_cast<const bfx8*>(&a_lds[wm + f * 16 + lr][lk * 8]);
      bfr[f] = *reinterpret_cast<const bfx8*>(&b_lds[wn + f * 16 + lr][lk * 8]);
    }
#pragma unroll
    for (int fm = 0; fm < 2; ++fm)
#pragma unroll
      for (int fj = 0; fj < 2; ++fj)
        acc[fm][fj] = __builtin_amdgcn_mfma_f32_16x16x32_bf16(af[fm], bfr[fj], acc[fm][fj], 0, 0, 0);
    __syncthreads();
  }
#pragma unroll
  for (int fm = 0; fm < 2; ++fm)
#pragma unroll
    for (int fj = 0; fj < 2; ++fj) {
      const int col = n0 + wn + fj * 16 + lr;
      if (col < N) {
        const float bb = bias[col];
#pragma unroll
        for (int q = 0; q < 4; ++q) {
          const int row = m0 + wm + fm * 16 + lk * 4 + q;
          O[(size_t)row * ldo + col] = acc[fm][fj][q] + bb;
        }
      }
    }
}

__global__ void build_zf(const float* __restrict__ mu, const float* __restrict__ lv,
                         const float* __restrict__ eps, const float* __restrict__ genre,
                         float* __restrict__ z) {
  int i = blockIdx.x * 256 + threadIdx.x;
  int b = i >> 10, c = i & 1023;
  z[i] = (c < LATM) ? mu[(size_t)b * LATM + c] + expf(0.5f * lv[(size_t)b * LATM + c]) * eps[(size_t)b * LATM + c]
                    : genre[b * NGENRE + (c - LATM)];
}

// ---------------- host ----------------
extern "C" void kernel_launch(void* const* d_in, const int* in_sizes, int n_in,
                              void* d_out, int out_size, void* d_ws, size_t ws_size,
                              hipStream_t stream) {
  const float* x      = (const float*)d_in[0];
  const float* genre  = (const float*)d_in[1];
  const float* eps    = (const float*)d_in[2];
  const float* eWih   = (const float*)d_in[3];
  const float* eWhh   = (const float*)d_in[4];
  const float* eBih   = (const float*)d_in[5];
  const float* eBhh   = (const float*)d_in[6];
  const float* dWih   = (const float*)d_in[7];
  const float* dWhh   = (const float*)d_in[8];
  const float* dBih   = (const float*)d_in[9];
  const float* dBhh   = (const float*)d_in[10];
  const float* fcMuW  = (const float*)d_in[11];
  const float* fcMuB  = (const float*)d_in[12];
  const float* fcLvW  = (const float*)d_in[13];
  const float* fcLvB  = (const float*)d_in[14];
  const float* fcOutW = (const float*)d_in[15];
  const float* fcOutB = (const float*)d_in[16];
  const float* fcDecW = (const float*)d_in[17];
  const float* fcDecB = (const float*)d_in[18];

  float* out = (float*)d_out;
  float* muO = out + (size_t)TT * BB * INDIM;
  float* lvO = muO + (size_t)BB * LATM;

  const size_t nEih = (size_t)3 * HD * XKP;
  const size_t nEhh = (size_t)3 * HD * HD;
  const size_t nDih = (size_t)3 * HD * INDIM;
  const size_t nDhh = (size_t)3 * HD * HD;
  const size_t nMu  = (size_t)1024 * HD;
  const size_t nOut = (size_t)HD * LATD;
  const size_t nDec = (size_t)INDIM * HD;
  const size_t oEih = 0;
  const size_t oEhh = oEih + nEih;
  const size_t oDih = oEhh + nEhh;
  const size_t oDhh = oDih + nDih;
  const size_t oMu  = oDhh + nDhh;
  const size_t oLv  = oMu + nMu;
  const size_t oOut = oLv + nMu;
  const size_t oDec = oOut + nOut;
  const size_t wTot = oDec + nDec;

  const size_t bytesW  = wTot * 2;
  const size_t bytesHF = (size_t)BB * HD * 4;
  const size_t bytesHB = (size_t)BB * HD * 2;
  const size_t bytesZB = (size_t)BB * LATD * 2;
  const size_t bytesNB = (size_t)BB * INDIM * 2;
  const size_t bytesX1 = (size_t)BB * XKP * 2;
  const size_t bytesXB = (size_t)TT * BB * XKP * 2;
  const size_t needB = bytesW + 2 * bytesHF + 2 * bytesHB + bytesZB + bytesNB + bytesX1 + 1024;
  const size_t needA = needB + bytesXB;
  const size_t bytesWdT  = (size_t)HD * 512 * 2;
  const size_t bytesWcB  = (size_t)3 * HD * HD * 2;
  const size_t bytesWcF  = (size_t)3 * HD * HD * 4;
  const size_t bytesWp   = (size_t)4 * HD * HD * 2;
  const size_t bytesBc   = (size_t)3 * HD * 4;
  const size_t bytesB4   = (size_t)HD * 16;
  const size_t bytesZero = (size_t)GIW * 4;
  const size_t bytesHist = (size_t)CHUNK * BB * HD * 2;
  const size_t needC = needA + bytesWdT + bytesWcB + bytesWcF + 2 * bytesWp +
                       bytesBc + 2 * bytesB4 + bytesZero + bytesHist + 1024;
  const size_t bytesGi = (size_t)TT * BB * GIW * 2;     // 805 MB
  const size_t needD = needC + bytesGi;

  if (ws_size >= needB) {
    const bool haveXB = (ws_size >= needA);
    const bool haveCP = (ws_size >= needC);
    const bool haveGI = (ws_size >= needD);
    char* p = (char*)d_ws;
    bf16_t* wb = (bf16_t*)p;            p += bytesW;
    float* h0  = (float*)p;             p += bytesHF;
    float* h1  = (float*)p;             p += bytesHF;
    bf16_t* hb0 = (bf16_t*)p;           p += bytesHB;
    bf16_t* hb1 = (bf16_t*)p;           p += bytesHB;
    bf16_t* zb  = (bf16_t*)p;           p += bytesZB;
    bf16_t* nb  = (bf16_t*)p;           p += bytesNB;
    bf16_t* x1  = (bf16_t*)p;           p += bytesX1;
    bf16_t* xb  = haveXB ? (bf16_t*)p : nullptr;
    if (haveXB) p += bytesXB;
    bf16_t *wdT = nullptr, *wcB = nullptr, *wP = nullptr, *wP0 = nullptr, *hist = nullptr;
    float *wcF = nullptr, *bc = nullptr, *zerosb = nullptr;
    float4 *b4D = nullptr, *b4D0 = nullptr;
    bf16_t *gix = nullptr;
    if (haveCP) {
      wdT = (bf16_t*)p;  p += bytesWdT;
      wcB = (bf16_t*)p;  p += bytesWcB;
      wP  = (bf16_t*)p;  p += bytesWp;
      wP0 = (bf16_t*)p;  p += bytesWp;
      wcF = (float*)p;   p += bytesWcF;
      bc  = (float*)p;   p += bytesBc;
      b4D = (float4*)p;  p += bytesB4;
      b4D0 = (float4*)p; p += bytesB4;
      zerosb = (float*)p; p += bytesZero;
      hist = (bf16_t*)p; p += bytesHist;
    }
    if (haveGI) { gix = (bf16_t*)p; p += bytesGi; }

    auto cast = [&](const float* s, bf16_t* d, int rs, int rp, int K, int ldp) {
      int g = rp > 8192 ? 8192 : rp;
      wcast_pad<<<g, 256, 0, stream>>>(s, d, rs, rp, K, ldp);
    };
    cast(eWih,   wb + oEih, 3 * HD, 3 * HD, XK,    XKP);
    cast(eWhh,   wb + oEhh, 3 * HD, 3 * HD, HD,    HD);
    cast(dWih,   wb + oDih, 3 * HD, 3 * HD, INDIM, INDIM);
    cast(dWhh,   wb + oDhh, 3 * HD, 3 * HD, HD,    HD);
    cast(fcMuW,  wb + oMu,  LATM,   1024,   HD,    HD);
    cast(fcLvW,  wb + oLv,  LATM,   1024,   HD,    HD);
    cast(fcOutW, wb + oOut, HD,     HD,     LATD,  LATD);
    cast(fcDecW, wb + oDec, INDIM,  INDIM,  HD,    HD);
    if (haveXB) cast(x, xb, TT * BB, TT * BB, XK, XKP);

    if (haveCP) {
      hipMemsetAsync(zerosb, 0, bytesZero, stream);
      wtransp<<<(HD * 512) / 256, 256, 0, stream>>>(fcDecW, wdT);
      gemm_nt3<<<dim3(HD / 64, (3 * HD) / 64), 256, 0, stream>>>(
          wb + oDih, INDIM, INDIM, wdT, INDIM, zerosb, wcF, HD, HD, wcB, HD);
      bcomp<<<(3 * HD) / 256, 256, 0, stream>>>(dWih, fcDecB, bc);
      biasbuild<<<HD / 256, 256, 0, stream>>>(bc, dBih, dBhh, b4D, b4D0);
      wprime<<<4096, 256, 0, stream>>>(wcB, wb + oDhh, wP, wP0);
    }
    if (haveGI) {
      // gi = x @ eWih^T for ALL timesteps: [65536 x 6144], K = XKP
      gemm_nt3<<<dim3(GIW / 64, (TT * BB) / 64), 256, 0, stream>>>(
          xb, XKP, XKP, wb + oEih, XKP, zerosb, nullptr, 0, GIW, gix, GIW);
    }

    hipMemsetAsync(h0, 0, bytesHF, stream);
    hipMemsetAsync(hb0, 0, bytesHB, stream);

    float*  hF[2] = {h0, h1};
    bf16_t* hB[2] = {hb0, hb1};

    // ---- encoder ----
    if (haveGI) {
      for (int t = 0; t < TT; ++t) {
        const int ci = t & 1, co = ci ^ 1;
        gruE<<<512, 256, 0, stream>>>(gix + (size_t)t * BB * GIW, hB[ci], wb + oEhh,
                                      hF[ci], eBih, eBhh, hF[co], hB[co]);
      }
    } else {
      for (int t = 0; t < TT; ++t) {
        const int ci = t & 1, co = ci ^ 1;
        const bf16_t* xt;
        if (haveXB) {
          xt = xb + (size_t)t * BB * XKP;
        } else {
          wcast_pad<<<512, 256, 0, stream>>>(x + (size_t)t * BB * XK, x1, BB, BB, XK, XKP);
          xt = x1;
        }
        gru6<<<512, 256, 0, stream>>>(xt, XKP, XKP / 64,
                                      wb + oEih, XKP, hB[ci], wb + oEhh,
                                      hF[ci], eBih, eBhh, hF[co], hB[co]);
      }
    }
    // h_enc = hF[0]/hB[0]
    gemm_nt3<<<dim3(16, 8), 256, 0, stream>>>(hB[0], HD, HD, wb + oMu, HD, fcMuB,
                                              muO, LATM, LATM, nullptr, 0);
    gemm_nt3<<<dim3(16, 8), 256, 0, stream>>>(hB[0], HD, HD, wb + oLv, HD, fcLvB,
                                              lvO, LATM, LATM, nullptr, 0);
    build_zb<<<(BB * LATD) / 256, 256, 0, stream>>>(muO, lvO, eps, genre, zb);
    gemm_nt3<<<dim3(32, 8), 256, 0, stream>>>(zb, LATD, LATD, wb + oOut, LATD, fcOutB,
                                              hF[0], HD, HD, hB[0], HD);
    // ---- decoder ----
    if (haveCP) {
      for (int t = 0; t < TT; ++t) {
        const bf16_t* hprev = (t == 0) ? hB[0] : hist + (size_t)((t - 1) & (CHUNK - 1)) * BB * HD;
        gruC2<<<512, 256, 0, stream>>>(hprev, t ? wP : wP0, t ? b4D : b4D0,
                                       hF[t & 1], hF[(t & 1) ^ 1],
                                       hist + (size_t)(t & (CHUNK - 1)) * BB * HD);
        if ((t & (CHUNK - 1)) == CHUNK - 1) {
          gemm_nt3<<<dim3(INDIM / 64, (CHUNK * BB) / 64), 256, 0, stream>>>(
              hist, HD, HD, wb + oDec, HD, fcDecB,
              out + (size_t)(t - (CHUNK - 1)) * BB * INDIM, INDIM, INDIM, nullptr, 0);
        }
      }
    } else {
      for (int t = 0; t < TT; ++t) {
        const int ci = t & 1, co = ci ^ 1;
        gru6<<<512, 256, 0, stream>>>(t ? nb : (const bf16_t*)nullptr, INDIM,
                                      t ? INDIM / 64 : 0,
                                      wb + oDih, INDIM, hB[ci], wb + oDhh,
                                      hF[ci], dBih, dBhh, hF[co], hB[co]);
        gemm_nt3<<<dim3(8, 8), 256, 0, stream>>>(hB[co], HD, HD, wb + oDec, HD, fcDecB,
                                                 out + (size_t)t * BB * INDIM, INDIM, INDIM,
                                                 nb, INDIM);
      }
    }
  } else {
    // ---- fp32 fallback ----
    float* h0 = (float*)d_ws;
    float* h1 = h0 + (size_t)BB * HD;
    float* zb = h1 + (size_t)BB * HD;
    hipMemsetAsync(h0, 0, (size_t)BB * HD * sizeof(float), stream);
    float* hF[2] = {h0, h1};
    for (int t = 0; t < TT; ++t) {
      const int ci = t & 1, co = ci ^ 1;
      gru_stepF<<<256, 256, 0, stream>>>(x + (size_t)t * BB * XK, XK, XK, eWih,
                                         hF[ci], eWhh, eBih, eBhh, hF[co]);
    }
    gemm_ntF<<<dim3(16, 8), 256, 0, stream>>>(hF[0], HD, HD, fcMuW, fcMuB, muO, LATM, LATM);
    gemm_ntF<<<dim3(16, 8), 256, 0, stream>>>(hF[0], HD, HD, fcLvW, fcLvB, lvO, LATM, LATM);
    build_zf<<<(BB * LATD) / 256, 256, 0, stream>>>(muO, lvO, eps, genre, zb);
    gemm_ntF<<<dim3(32, 8), 256, 0, stream>>>(zb, LATD, LATD, fcOutW, fcOutB, hF[0], HD, HD);
    for (int t = 0; t < TT; ++t) {
      const int ci = t & 1, co = ci ^ 1;
      gru_stepF<<<256, 256, 0, stream>>>(t ? out + (size_t)(t - 1) * BB * INDIM : nullptr,
                                         INDIM, INDIM, dWih, hF[ci], dWhh, dBih, dBhh, hF[co]);
      gemm_ntF<<<dim3(8, 8), 256, 0, stream>>>(hF[co], HD, HD, fcDecW, fcDecB,
                                               out + (size_t)t * BB * INDIM, INDIM, INDIM);
    }
  }
  (void)in_sizes; (void)n_in; (void)out_size;
}